// Round 5
// baseline (344.406 us; speedup 1.0000x reference)
//
#include <hip/hip_runtime.h>
#include <math.h>

// QTGNN: GRU(10 steps, hidden16) -> QGAT layer1 -> QGAT layer2 -> linear head.
// N=10000 nodes, E=320000 edges (+N self loops). All fp32.
// R1: GRU 16 threads/node (shfl matvec) — fixed 256-VGPR spill + 1.7% occupancy.
// R2: fused attention into msg kernel, dropped global-max (softmax shift-invariant
//     up to the 1e-8 eps; validated absmax 0.0).
// R3 post-mortem: XCD-replica atomics DID NOT reduce WRITE_SIZE (50.8 vs 50.3 MB)
//     — device-scope atomics resolve past L2 at the coherence point regardless of
//     replica locality; 5 atomics/edge x 32B sector = the 50MB = ~88us at the
//     observed scattered-RMW rate. Fix here (R4): CSR-by-dst built once per call
//     (histogram + scan + fill, int atomics only), then gather-mode QGAT:
//     32 lanes/node recompute circuit per in-edge in registers, shfl-reduce,
//     fused node update. Zero float atomics. Rep-0 product-state + wire-0 RY
//     merge shave ~10% circuit FLOPs.
// R5: identical to R4 — previous round's bench was lost to a GPU acquisition
//     timeout (no counters); resubmitting unchanged.

#define GH 16
#define SEQ 10
#define PI_F 3.14159265358979323846f

__device__ __forceinline__ float sigmoidf_(float x) { return 1.0f / (1.0f + expf(-x)); }

// ---------------- GRU (16 threads/node) + layer-1 ELU projection + angle precompute ----------------
__global__ __launch_bounds__(256) void k_gru(
    const float* __restrict__ x, const float* __restrict__ W_ih,
    const float* __restrict__ W_hh, const float* __restrict__ b_ih,
    const float* __restrict__ b_hh, const float* __restrict__ p1W,
    const float* __restrict__ p1b, const float* __restrict__ q1w,
    const float* __restrict__ q2w, float* __restrict__ h1,
    float* __restrict__ cs1, float* __restrict__ qcs, int N)
{
    __shared__ float sW[48 * 16];
    __shared__ float sp1W[4 * 19], sp1b[4];
    for (int i = threadIdx.x; i < 48 * 16; i += 256) sW[i] = W_hh[i];
    if (threadIdx.x < 76) sp1W[threadIdx.x] = p1W[threadIdx.x];
    if (threadIdx.x < 4) sp1b[threadIdx.x] = p1b[threadIdx.x];
    __syncthreads();

    // uniform weight-gate angle table (both layers), once on block 0
    if (blockIdx.x == 0 && threadIdx.x < 12) {
        const float* qw = (threadIdx.x < 6) ? q1w : q2w;
        int rd = threadIdx.x % 6;
        float sy, cy; sincosf(0.5f * qw[rd * 2 + 0], &sy, &cy);
        float sz, cz; sincosf(0.5f * qw[rd * 2 + 1], &sz, &cz);
        float* q = qcs + threadIdx.x * 4;
        q[0] = cy; q[1] = sy; q[2] = cz; q[3] = sz;
    }

    const int j = threadIdx.x & 15;          // hidden unit
    const int n = blockIdx.x * 16 + (threadIdx.x >> 4);
    const bool valid = (n < N);

    float wr[GH], wz[GH], wn[GH];
#pragma unroll
    for (int k = 0; k < GH; ++k) {
        wr[k] = sW[j * 16 + k];
        wz[k] = sW[(16 + j) * 16 + k];
        wn[k] = sW[(32 + j) * 16 + k];
    }
    float wir = W_ih[j], wiz = W_ih[16 + j], win_ = W_ih[32 + j];
    float bir = b_ih[j], biz = b_ih[16 + j], bin_ = b_ih[32 + j];
    float brr = b_hh[j], brz = b_hh[16 + j], brn = b_hh[32 + j];

    float xv[13];
#pragma unroll
    for (int t = 0; t < 13; ++t) xv[t] = valid ? x[n * 13 + t] : 0.f;

    float h = 0.f;
#pragma unroll
    for (int t = 0; t < SEQ; ++t) {
        float xt = xv[t];
        float ghr = brr, ghz = brz, ghn = brn;
#pragma unroll
        for (int k = 0; k < GH; ++k) {
            float hk = __shfl(h, k, 16);
            ghr += wr[k] * hk; ghz += wz[k] * hk; ghn += wn[k] * hk;
        }
        float r  = sigmoidf_(xt * wir + bir + ghr);
        float z  = sigmoidf_(xt * wiz + biz + ghz);
        float nv = tanhf(xt * win_ + bin_ + r * ghn);
        h = (1.f - z) * nv + z * h;
    }

    // proj1: elu([h, x[10:13]] @ p1W.T + p1b) via 16-lane butterfly
    float s0 = h * sp1W[0 * 19 + j];
    float s1 = h * sp1W[1 * 19 + j];
    float s2 = h * sp1W[2 * 19 + j];
    float s3 = h * sp1W[3 * 19 + j];
#pragma unroll
    for (int m = 1; m < 16; m <<= 1) {
        s0 += __shfl_xor(s0, m, 16);
        s1 += __shfl_xor(s1, m, 16);
        s2 += __shfl_xor(s2, m, 16);
        s3 += __shfl_xor(s3, m, 16);
    }
    if (valid && j < 4) {
        float s = (j == 0) ? s0 : (j == 1) ? s1 : (j == 2) ? s2 : s3;
        s += sp1b[j] + xv[10] * sp1W[j * 19 + 16] + xv[11] * sp1W[j * 19 + 17]
           + xv[12] * sp1W[j * 19 + 18];
        float hv = (s > 0.f) ? s : expm1f(s);
        h1[n * 4 + j] = hv;
        float sv, cv; sincosf(0.5f * PI_F * tanhf(hv), &sv, &cv);
        cs1[n * 8 + 2 * j]     = cv;
        cs1[n * 8 + 2 * j + 1] = sv;
    }
}

// ---------------- CSR build: degree histogram, scan, fill ----------------
__global__ __launch_bounds__(256) void k_deg(
    const int* __restrict__ ei, int* __restrict__ deg, int E)
{
    int e = blockIdx.x * 256 + threadIdx.x;
    if (e < E) atomicAdd(&deg[ei[E + e]], 1);   // dst row
}

__global__ __launch_bounds__(256) void k_scan(
    const int* __restrict__ deg, int* __restrict__ off,
    int* __restrict__ cur, int N)
{
    __shared__ int part[256];
    const int t = threadIdx.x;
    const int chunk = (N + 255) / 256;
    const int lo = t * chunk;
    const int hi = min(lo + chunk, N);
    int s = 0;
    for (int i = lo; i < hi; ++i) s += deg[i];
    part[t] = s;
    __syncthreads();
    for (int d = 1; d < 256; d <<= 1) {
        int y = (t >= d) ? part[t - d] : 0;
        __syncthreads();
        part[t] += y;
        __syncthreads();
    }
    int run = part[t] - s;   // exclusive base for this chunk
    for (int i = lo; i < hi; ++i) {
        off[i] = run; cur[i] = run; run += deg[i];
    }
}

__global__ __launch_bounds__(256) void k_fill(
    const int* __restrict__ ei, int* __restrict__ cur,
    int* __restrict__ csr, int E)
{
    int e = blockIdx.x * 256 + threadIdx.x;
    if (e < E) {
        int slot = atomicAdd(&cur[ei[E + e]], 1);
        csr[slot] = e;
    }
}

// ---------------- quantum gate helpers (all indices compile-time) ----------------
template <int STR>
__device__ __forceinline__ void ry_g(float (&sr)[16], float (&si)[16], float c, float s) {
#pragma unroll
    for (int i0 = 0; i0 < 16; ++i0) {
        if (i0 & STR) continue;
        int i1 = i0 | STR;
        float a0r = sr[i0], a0i = si[i0], a1r = sr[i1], a1i = si[i1];
        sr[i0] = c * a0r - s * a1r; si[i0] = c * a0i - s * a1i;
        sr[i1] = s * a0r + c * a1r; si[i1] = s * a0i + c * a1i;
    }
}
template <int STR>
__device__ __forceinline__ void rz_g(float (&sr)[16], float (&si)[16], float c, float s) {
#pragma unroll
    for (int i = 0; i < 16; ++i) {
        float r = sr[i], im = si[i];
        if (i & STR) { sr[i] = r * c - im * s; si[i] = im * c + r * s; }
        else         { sr[i] = r * c + im * s; si[i] = im * c - r * s; }
    }
}
template <int SC, int ST>
__device__ __forceinline__ void cnot_g(float (&sr)[16], float (&si)[16]) {
#pragma unroll
    for (int i = 0; i < 16; ++i) {
        if ((i & SC) && !(i & ST)) {
            int j = i | ST;
            float tr = sr[i], ti = si[i];
            sr[i] = sr[j]; si[i] = si[j]; sr[j] = tr; si[j] = ti;
        }
    }
}

// circuit: mc/ms = merged wire-0 half-angle (input RY + corr RY), c1..s3 = wires 1-3
__device__ __forceinline__ void qcirc(
    float mc, float ms, float c1, float s1, float c2, float s2,
    float c3, float s3, const float* __restrict__ qc, float (&z)[4])
{
    float sr[16], si[16];
    // rep 0 input layer on |0000>: product state (real), exact same factor products
    float t0 = mc * c1, t1 = mc * s1, t2 = ms * c1, t3 = ms * s1;
    float u0 = c2 * c3, u1 = c2 * s3, u2 = s2 * c3, u3 = s2 * s3;
    sr[0]  = t0 * u0; sr[1]  = t0 * u1; sr[2]  = t0 * u2; sr[3]  = t0 * u3;
    sr[4]  = t1 * u0; sr[5]  = t1 * u1; sr[6]  = t1 * u2; sr[7]  = t1 * u3;
    sr[8]  = t2 * u0; sr[9]  = t2 * u1; sr[10] = t2 * u2; sr[11] = t2 * u3;
    sr[12] = t3 * u0; sr[13] = t3 * u1; sr[14] = t3 * u2; sr[15] = t3 * u3;
#pragma unroll
    for (int i = 0; i < 16; ++i) si[i] = 0.f;

#pragma unroll
    for (int r = 0; r < 3; ++r) {
        if (r > 0) {  // reps 1,2: input RY layer (wire0 merged with corr)
            ry_g<8>(sr, si, mc, ms);
            ry_g<4>(sr, si, c1, s1);
            ry_g<2>(sr, si, c2, s2);
            ry_g<1>(sr, si, c3, s3);
        }
#pragma unroll
        for (int d = 0; d < 2; ++d) {
            int rd = r * 2 + d;
            float cy = qc[rd * 4 + 0], sy = qc[rd * 4 + 1];
            float cz = qc[rd * 4 + 2], sz = qc[rd * 4 + 3];
            ry_g<8>(sr, si, cy, sy); rz_g<8>(sr, si, cz, sz);
            ry_g<4>(sr, si, cy, sy); rz_g<4>(sr, si, cz, sz);
            ry_g<2>(sr, si, cy, sy); rz_g<2>(sr, si, cz, sz);
            ry_g<1>(sr, si, cy, sy); rz_g<1>(sr, si, cz, sz);
            if (d == 0) { cnot_g<8, 4>(sr, si); cnot_g<2, 1>(sr, si); }
            else        { cnot_g<4, 2>(sr, si); }
        }
    }

    float p[16];
#pragma unroll
    for (int i = 0; i < 16; ++i) p[i] = sr[i] * sr[i] + si[i] * si[i];
#pragma unroll
    for (int w = 0; w < 4; ++w) {
        const int STR = 8 >> w;
        float zz = 0.f;
#pragma unroll
        for (int i = 0; i < 16; ++i) zz += (i & STR) ? -p[i] : p[i];
        z[w] = zz;
    }
}

// ---------------- gather-mode QGAT: 32 lanes/node, fused node update ----------------
template <bool FINAL>
__global__ __launch_bounds__(256) void k_qgat(
    const int* __restrict__ off, const int* __restrict__ deg,
    const int* __restrict__ csr, const int* __restrict__ ei,
    const float* __restrict__ ea, const float* __restrict__ h,
    const float* __restrict__ cs, const float* __restrict__ Wa,
    const float* __restrict__ qcsL, const float* __restrict__ g4,
    const float* __restrict__ be4, const float* __restrict__ pW,
    const float* __restrict__ pb, const float* __restrict__ rW,
    const float* __restrict__ rb, float* __restrict__ oh,
    float* __restrict__ ocs, float* __restrict__ out, int E, int N)
{
    const int lane = threadIdx.x & 31;
    const int n = blockIdx.x * 8 + (threadIdx.x >> 5);
    if (n >= N) return;

    float wa[8];
#pragma unroll
    for (int i = 0; i < 8; ++i) wa[i] = Wa[i];
    float qc[24];
#pragma unroll
    for (int i = 0; i < 24; ++i) qc[i] = qcsL[i];

    const float4 hd = *reinterpret_cast<const float4*>(&h[n * 4]);
    const int dg = deg[n];
    const int base = off[n];

    float acc0 = 0.f, acc1 = 0.f, acc2 = 0.f, acc3 = 0.f, acc4 = 0.f;

    for (int k = lane; k < dg + 1; k += 32) {
        int src; float eav;
        if (k == 0) { src = n; eav = 1.0f; }          // self-loop
        else { int e = csr[base + k - 1]; src = ei[e]; eav = ea[e]; }

        // attention logit -> unnormalized softmax weight (no max shift; validated)
        float4 hs = *reinterpret_cast<const float4*>(&h[src * 4]);
        float s0 = hs.x * wa[0] + hs.y * wa[1] + hs.z * wa[2] + hs.w * wa[3]
                 + hd.x * wa[4] + hd.y * wa[5] + hd.z * wa[6] + hd.w * wa[7];
        s0 = (s0 > 0.f) ? s0 : 0.2f * s0;
        float aexp = expf(s0 * fabsf(eav));

        // per-source input angles + per-edge corr angle; merge wire-0 RY pair
        float4 c01 = *reinterpret_cast<const float4*>(&cs[src * 8]);
        float4 c23 = *reinterpret_cast<const float4*>(&cs[src * 8 + 4]);
        float scv, ccv; sincosf(0.5f * PI_F * tanhf(eav), &scv, &ccv);
        float mc = c01.x * ccv - c01.y * scv;   // cos((th0+thc)/2)
        float ms = c01.y * ccv + c01.x * scv;   // sin((th0+thc)/2)

        float z[4];
        qcirc(mc, ms, c01.z, c01.w, c23.x, c23.y, c23.z, c23.w, qc, z);

        acc0 += aexp * z[0]; acc1 += aexp * z[1];
        acc2 += aexp * z[2]; acc3 += aexp * z[3];
        acc4 += aexp;
    }

#pragma unroll
    for (int m = 1; m < 32; m <<= 1) {
        acc0 += __shfl_xor(acc0, m, 32);
        acc1 += __shfl_xor(acc1, m, 32);
        acc2 += __shfl_xor(acc2, m, 32);
        acc3 += __shfl_xor(acc3, m, 32);
        acc4 += __shfl_xor(acc4, m, 32);
    }

    float dn = acc4 + 1e-8f;
    float v0 = acc0 / dn + hd.x, v1 = acc1 / dn + hd.y;
    float v2 = acc2 / dn + hd.z, v3 = acc3 / dn + hd.w;
    float mu = 0.25f * (v0 + v1 + v2 + v3);
    float d0 = v0 - mu, d1 = v1 - mu, d2 = v2 - mu, d3 = v3 - mu;
    float var = 0.25f * (d0 * d0 + d1 * d1 + d2 * d2 + d3 * d3);
    float rs = 1.0f / sqrtf(var + 1e-5f);
    float y0 = d0 * rs * g4[0] + be4[0];
    float y1 = d1 * rs * g4[1] + be4[1];
    float y2 = d2 * rs * g4[2] + be4[2];
    float y3 = d3 * rs * g4[3] + be4[3];

    if (FINAL) {
        if (lane == 0)
            out[n] = rb[0] + y0 * rW[0] + y1 * rW[1] + y2 * rW[2] + y3 * rW[3];
    } else {
        y0 = fmaxf(y0, 0.f); y1 = fmaxf(y1, 0.f);
        y2 = fmaxf(y2, 0.f); y3 = fmaxf(y3, 0.f);
        if (lane < 4) {
            float s = pb[lane] + y0 * pW[lane * 4 + 0] + y1 * pW[lane * 4 + 1]
                    + y2 * pW[lane * 4 + 2] + y3 * pW[lane * 4 + 3];
            float hv = (s > 0.f) ? s : expm1f(s);
            oh[n * 4 + lane] = hv;
            float sv, cv; sincosf(0.5f * PI_F * tanhf(hv), &sv, &cv);
            ocs[n * 8 + 2 * lane]     = cv;
            ocs[n * 8 + 2 * lane + 1] = sv;
        }
    }
}

extern "C" void kernel_launch(void* const* d_in, const int* in_sizes, int n_in,
                              void* d_out, int out_size, void* d_ws, size_t ws_size,
                              hipStream_t stream)
{
    const float* x    = (const float*)d_in[0];
    const int*   ei   = (const int*)d_in[1];
    const float* ea   = (const float*)d_in[2];
    const float* W_ih = (const float*)d_in[3];
    const float* W_hh = (const float*)d_in[4];
    const float* b_ih = (const float*)d_in[5];
    const float* b_hh = (const float*)d_in[6];
    const float* p1W  = (const float*)d_in[7];
    const float* p1b  = (const float*)d_in[8];
    const float* a1W  = (const float*)d_in[9];
    const float* q1w  = (const float*)d_in[10];
    const float* g1   = (const float*)d_in[11];
    const float* be1  = (const float*)d_in[12];
    const float* p2W  = (const float*)d_in[13];
    const float* p2b  = (const float*)d_in[14];
    const float* a2W  = (const float*)d_in[15];
    const float* q2w  = (const float*)d_in[16];
    const float* g2   = (const float*)d_in[17];
    const float* be2  = (const float*)d_in[18];
    const float* rW   = (const float*)d_in[19];
    const float* rb   = (const float*)d_in[20];
    float* out = (float*)d_out;

    int N = in_sizes[0] / 13;
    int E = in_sizes[1] / 2;

    // workspace layout
    float* ws  = (float*)d_ws;
    float* h1  = ws;                      // N*4
    float* h2  = h1 + (size_t)N * 4;      // N*4
    float* cs1 = h2 + (size_t)N * 4;      // N*8
    float* cs2 = cs1 + (size_t)N * 8;     // N*8
    float* qcs = cs2 + (size_t)N * 8;     // 64 (48 used)
    int* deg = (int*)(qcs + 64);          // N (zeroed)
    int* off = deg + N;                   // N
    int* cur = off + N;                   // N
    int* csr = cur + N;                   // E

    hipMemsetAsync(deg, 0, (size_t)N * sizeof(int), stream);

    const int B = 256;
    k_gru<<<(N + 15) / 16, B, 0, stream>>>(x, W_ih, W_hh, b_ih, b_hh, p1W, p1b,
                                           q1w, q2w, h1, cs1, qcs, N);

    // CSR build (used by both layers)
    k_deg<<<(E + B - 1) / B, B, 0, stream>>>(ei, deg, E);
    k_scan<<<1, B, 0, stream>>>(deg, off, cur, N);
    k_fill<<<(E + B - 1) / B, B, 0, stream>>>(ei, cur, csr, E);

    // layer 1: gather + node update -> h2, cs2
    k_qgat<false><<<(N + 7) / 8, B, 0, stream>>>(
        off, deg, csr, ei, ea, h1, cs1, a1W, qcs, g1, be1, p2W, p2b,
        rW, rb, h2, cs2, out, E, N);

    // layer 2: gather + node update -> out
    k_qgat<true><<<(N + 7) / 8, B, 0, stream>>>(
        off, deg, csr, ei, ea, h2, cs2, a2W, qcs + 24, g2, be2, p2W, p2b,
        rW, rb, h2, cs2, out, E, N);
}

// Round 6
// 312.030 us; speedup vs baseline: 1.1038x; 1.1038x over previous
//
#include <hip/hip_runtime.h>
#include <math.h>

// QTGNN: GRU(10 steps, hidden16) -> QGAT layer1 -> QGAT layer2 -> linear head.
// N=10000 nodes, E=320000 edges (+N self loops). All fp32.
// R1: GRU 16 threads/node (shfl matvec) — fixed 256-VGPR spill + 1.7% occupancy.
// R2: fused attention into msg kernel, dropped global-max (softmax shift-invariant
//     up to the 1e-8 eps; validated absmax 0.0).
// R3: XCD-replica atomics refuted — device-scope atomics RMW at the coherence
//     point regardless of locality (WRITE_SIZE unchanged at 50MB).
// R4/R5: gather-mode CSR QGAT. WRITE_SIZE 50MB->0.5MB (atomics gone) but dur
//     flat: FETCH rose to 12.8MB @144GB/s — latency-bound on 4 dependent
//     scattered loads/edge (csr->ei/ea->cs->h), occupancy 19% (tail).
// R6: kill the scatter chain: (a) k_fill writes {src,ea} float2 records in CSR
//     order -> edge stream fully coalesced; (b) 64B node records pack
//     cs[8]+hsdot+h[4] -> ONE scattered line per edge; attention dot split into
//     per-node hsdot/hddot precomputed in the previous kernel's epilogue;
//     (c) k_scan counting-sorts nodes by descending degree -> balanced waves,
//     heavy nodes first; (d) k_deg fused into k_gru (grid-stride histogram).

#define GH 16
#define SEQ 10
#define PI_F 3.14159265358979323846f

__device__ __forceinline__ float sigmoidf_(float x) { return 1.0f / (1.0f + expf(-x)); }

// ---------------- GRU (16 threads/node) + proj1 + node-record/dot precompute
//                  + fused dst-degree histogram ----------------
__global__ __launch_bounds__(256) void k_gru(
    const float* __restrict__ x, const float* __restrict__ W_ih,
    const float* __restrict__ W_hh, const float* __restrict__ b_ih,
    const float* __restrict__ b_hh, const float* __restrict__ p1W,
    const float* __restrict__ p1b, const float* __restrict__ a1W,
    const float* __restrict__ q1w, const float* __restrict__ q2w,
    const int* __restrict__ ei, int* __restrict__ deg,
    float* __restrict__ nrec1, float* __restrict__ hdd1,
    float* __restrict__ qcs, int N, int E)
{
    // fused degree histogram over edge dst (grid-stride)
    for (int e = blockIdx.x * 256 + threadIdx.x; e < E; e += gridDim.x * 256)
        atomicAdd(&deg[ei[E + e]], 1);

    __shared__ float sW[48 * 16];
    __shared__ float sp1W[4 * 19], sp1b[4];
    for (int i = threadIdx.x; i < 48 * 16; i += 256) sW[i] = W_hh[i];
    if (threadIdx.x < 76) sp1W[threadIdx.x] = p1W[threadIdx.x];
    if (threadIdx.x < 4) sp1b[threadIdx.x] = p1b[threadIdx.x];
    __syncthreads();

    // uniform weight-gate angle table (both layers), once on block 0
    if (blockIdx.x == 0 && threadIdx.x < 12) {
        const float* qw = (threadIdx.x < 6) ? q1w : q2w;
        int rd = threadIdx.x % 6;
        float sy, cy; sincosf(0.5f * qw[rd * 2 + 0], &sy, &cy);
        float sz, cz; sincosf(0.5f * qw[rd * 2 + 1], &sz, &cz);
        float* q = qcs + threadIdx.x * 4;
        q[0] = cy; q[1] = sy; q[2] = cz; q[3] = sz;
    }

    const int j = threadIdx.x & 15;          // hidden unit
    const int n = blockIdx.x * 16 + (threadIdx.x >> 4);
    const bool valid = (n < N);

    float wr[GH], wz[GH], wn[GH];
#pragma unroll
    for (int k = 0; k < GH; ++k) {
        wr[k] = sW[j * 16 + k];
        wz[k] = sW[(16 + j) * 16 + k];
        wn[k] = sW[(32 + j) * 16 + k];
    }
    float wir = W_ih[j], wiz = W_ih[16 + j], win_ = W_ih[32 + j];
    float bir = b_ih[j], biz = b_ih[16 + j], bin_ = b_ih[32 + j];
    float brr = b_hh[j], brz = b_hh[16 + j], brn = b_hh[32 + j];

    float xv[13];
#pragma unroll
    for (int t = 0; t < 13; ++t) xv[t] = valid ? x[n * 13 + t] : 0.f;

    float h = 0.f;
#pragma unroll
    for (int t = 0; t < SEQ; ++t) {
        float xt = xv[t];
        float ghr = brr, ghz = brz, ghn = brn;
#pragma unroll
        for (int k = 0; k < GH; ++k) {
            float hk = __shfl(h, k, 16);
            ghr += wr[k] * hk; ghz += wz[k] * hk; ghn += wn[k] * hk;
        }
        float r  = sigmoidf_(xt * wir + bir + ghr);
        float z  = sigmoidf_(xt * wiz + biz + ghz);
        float nv = tanhf(xt * win_ + bin_ + r * ghn);
        h = (1.f - z) * nv + z * h;
    }

    // proj1: elu([h, x[10:13]] @ p1W.T + p1b) via 16-lane butterfly
    float s0 = h * sp1W[0 * 19 + j];
    float s1 = h * sp1W[1 * 19 + j];
    float s2 = h * sp1W[2 * 19 + j];
    float s3 = h * sp1W[3 * 19 + j];
#pragma unroll
    for (int m = 1; m < 16; m <<= 1) {
        s0 += __shfl_xor(s0, m, 16);
        s1 += __shfl_xor(s1, m, 16);
        s2 += __shfl_xor(s2, m, 16);
        s3 += __shfl_xor(s3, m, 16);
    }
    if (valid && j < 4) {
        float s = (j == 0) ? s0 : (j == 1) ? s1 : (j == 2) ? s2 : s3;
        s += sp1b[j] + xv[10] * sp1W[j * 19 + 16] + xv[11] * sp1W[j * 19 + 17]
           + xv[12] * sp1W[j * 19 + 18];
        float hv = (s > 0.f) ? s : expm1f(s);
        float* nb = nrec1 + (size_t)n * 16;
        float sv, cv; sincosf(0.5f * PI_F * tanhf(hv), &sv, &cv);
        nb[2 * j]     = cv;
        nb[2 * j + 1] = sv;
        nb[12 + j]    = hv;                      // residual copy of h1
        // attention dots: hsdot = h1.Wa[0:4], hddot = h1.Wa[4:8]
        float ds = hv * a1W[j];
        float dd = hv * a1W[4 + j];
        ds += __shfl_xor(ds, 1); ds += __shfl_xor(ds, 2);
        dd += __shfl_xor(dd, 1); dd += __shfl_xor(dd, 2);
        if (j == 0) { nb[8] = ds; hdd1[n] = dd; }
    }
}

// ---------------- scan + offsets + descending-degree counting sort ----------------
__global__ __launch_bounds__(256) void k_scan(
    const int* __restrict__ deg, int* __restrict__ off,
    int* __restrict__ cur, int* __restrict__ perm, int N)
{
    __shared__ int part[256];
    __shared__ int bins[256];
    const int t = threadIdx.x;
    const int chunk = (N + 255) / 256;
    const int lo = t * chunk;
    const int hi = min(lo + chunk, N);
    int s = 0;
    for (int i = lo; i < hi; ++i) s += deg[i];
    part[t] = s;
    bins[t] = 0;
    __syncthreads();
    for (int d = 1; d < 256; d <<= 1) {
        int y = (t >= d) ? part[t - d] : 0;
        __syncthreads();
        part[t] += y;
        __syncthreads();
    }
    int run = part[t] - s;   // exclusive base for this chunk
    for (int i = lo; i < hi; ++i) { off[i] = run; cur[i] = run; run += deg[i]; }
    // histogram with descending-degree key
    for (int i = lo; i < hi; ++i)
        atomicAdd(&bins[255 - min(deg[i], 255)], 1);
    __syncthreads();
    int bv = bins[t];
    part[t] = bv;
    __syncthreads();
    for (int d = 1; d < 256; d <<= 1) {
        int y = (t >= d) ? part[t - d] : 0;
        __syncthreads();
        part[t] += y;
        __syncthreads();
    }
    bins[t] = part[t] - bv;      // exclusive base per key
    __syncthreads();
    for (int i = lo; i < hi; ++i) {
        int key = 255 - min(deg[i], 255);
        int r = atomicAdd(&bins[key], 1);
        perm[r] = i;
    }
}

// ---------------- CSR fill: coalescable {src, ea} records ----------------
__global__ __launch_bounds__(256) void k_fill(
    const int* __restrict__ ei, const float* __restrict__ ea,
    int* __restrict__ cur, float2* __restrict__ rec, int E)
{
    int e = blockIdx.x * 256 + threadIdx.x;
    if (e < E) {
        int slot = atomicAdd(&cur[ei[E + e]], 1);
        float2 r; r.x = __int_as_float(ei[e]); r.y = ea[e];
        rec[slot] = r;
    }
}

// ---------------- quantum gate helpers (all indices compile-time) ----------------
template <int STR>
__device__ __forceinline__ void ry_g(float (&sr)[16], float (&si)[16], float c, float s) {
#pragma unroll
    for (int i0 = 0; i0 < 16; ++i0) {
        if (i0 & STR) continue;
        int i1 = i0 | STR;
        float a0r = sr[i0], a0i = si[i0], a1r = sr[i1], a1i = si[i1];
        sr[i0] = c * a0r - s * a1r; si[i0] = c * a0i - s * a1i;
        sr[i1] = s * a0r + c * a1r; si[i1] = s * a0i + c * a1i;
    }
}
template <int STR>
__device__ __forceinline__ void rz_g(float (&sr)[16], float (&si)[16], float c, float s) {
#pragma unroll
    for (int i = 0; i < 16; ++i) {
        float r = sr[i], im = si[i];
        if (i & STR) { sr[i] = r * c - im * s; si[i] = im * c + r * s; }
        else         { sr[i] = r * c + im * s; si[i] = im * c - r * s; }
    }
}
template <int SC, int ST>
__device__ __forceinline__ void cnot_g(float (&sr)[16], float (&si)[16]) {
#pragma unroll
    for (int i = 0; i < 16; ++i) {
        if ((i & SC) && !(i & ST)) {
            int j = i | ST;
            float tr = sr[i], ti = si[i];
            sr[i] = sr[j]; si[i] = si[j]; sr[j] = tr; si[j] = ti;
        }
    }
}

// circuit: mc/ms = merged wire-0 half-angle (input RY + corr RY), c1..s3 = wires 1-3
__device__ __forceinline__ void qcirc(
    float mc, float ms, float c1, float s1, float c2, float s2,
    float c3, float s3, const float* __restrict__ qc, float (&z)[4])
{
    float sr[16], si[16];
    // rep 0 input layer on |0000>: product state (real)
    float t0 = mc * c1, t1 = mc * s1, t2 = ms * c1, t3 = ms * s1;
    float u0 = c2 * c3, u1 = c2 * s3, u2 = s2 * c3, u3 = s2 * s3;
    sr[0]  = t0 * u0; sr[1]  = t0 * u1; sr[2]  = t0 * u2; sr[3]  = t0 * u3;
    sr[4]  = t1 * u0; sr[5]  = t1 * u1; sr[6]  = t1 * u2; sr[7]  = t1 * u3;
    sr[8]  = t2 * u0; sr[9]  = t2 * u1; sr[10] = t2 * u2; sr[11] = t2 * u3;
    sr[12] = t3 * u0; sr[13] = t3 * u1; sr[14] = t3 * u2; sr[15] = t3 * u3;
#pragma unroll
    for (int i = 0; i < 16; ++i) si[i] = 0.f;

#pragma unroll
    for (int r = 0; r < 3; ++r) {
        if (r > 0) {  // reps 1,2: input RY layer (wire0 merged with corr)
            ry_g<8>(sr, si, mc, ms);
            ry_g<4>(sr, si, c1, s1);
            ry_g<2>(sr, si, c2, s2);
            ry_g<1>(sr, si, c3, s3);
        }
#pragma unroll
        for (int d = 0; d < 2; ++d) {
            int rd = r * 2 + d;
            float cy = qc[rd * 4 + 0], sy = qc[rd * 4 + 1];
            float cz = qc[rd * 4 + 2], sz = qc[rd * 4 + 3];
            ry_g<8>(sr, si, cy, sy); rz_g<8>(sr, si, cz, sz);
            ry_g<4>(sr, si, cy, sy); rz_g<4>(sr, si, cz, sz);
            ry_g<2>(sr, si, cy, sy); rz_g<2>(sr, si, cz, sz);
            ry_g<1>(sr, si, cy, sy); rz_g<1>(sr, si, cz, sz);
            if (d == 0) { cnot_g<8, 4>(sr, si); cnot_g<2, 1>(sr, si); }
            else        { cnot_g<4, 2>(sr, si); }
        }
    }

    float p[16];
#pragma unroll
    for (int i = 0; i < 16; ++i) p[i] = sr[i] * sr[i] + si[i] * si[i];
#pragma unroll
    for (int w = 0; w < 4; ++w) {
        const int STR = 8 >> w;
        float zz = 0.f;
#pragma unroll
        for (int i = 0; i < 16; ++i) zz += (i & STR) ? -p[i] : p[i];
        z[w] = zz;
    }
}

// ---------------- gather-mode QGAT: 32 lanes/node (perm order), fused node update ----------------
template <bool FINAL>
__global__ __launch_bounds__(256) void k_qgat(
    const int* __restrict__ off, const int* __restrict__ deg,
    const int* __restrict__ perm, const float2* __restrict__ rec,
    const float* __restrict__ nrec, const float* __restrict__ hdd,
    const float* __restrict__ qcsL, const float* __restrict__ g4,
    const float* __restrict__ be4, const float* __restrict__ pW,
    const float* __restrict__ pb, const float* __restrict__ WaN,
    const float* __restrict__ rW, const float* __restrict__ rb,
    float* __restrict__ onrec, float* __restrict__ ohdd,
    float* __restrict__ out, int N)
{
    const int lane = threadIdx.x & 31;
    const int slot = blockIdx.x * 8 + (threadIdx.x >> 5);
    if (slot >= N) return;
    const int n = perm[slot];

    float qc[24];
#pragma unroll
    for (int i = 0; i < 24; ++i) qc[i] = qcsL[i];

    const float* nb = nrec + (size_t)n * 16;
    const float4 hd4 = *reinterpret_cast<const float4*>(nb + 12);
    const float hddN = hdd[n];
    const int dg = deg[n];
    const int base = off[n];

    float acc0 = 0.f, acc1 = 0.f, acc2 = 0.f, acc3 = 0.f, acc4 = 0.f;

    for (int k = lane; k < dg + 1; k += 32) {
        int src; float eav;
        if (k == 0) { src = n; eav = 1.0f; }          // self-loop
        else { float2 r = rec[base + k - 1]; src = __float_as_int(r.x); eav = r.y; }

        const float* sb = nrec + (size_t)src * 16;    // one 64B line per src
        float4 c01 = *reinterpret_cast<const float4*>(sb);
        float4 c23 = *reinterpret_cast<const float4*>(sb + 4);
        float s0 = sb[8] + hddN;                      // hsdot[src] + hddot[n]
        s0 = (s0 > 0.f) ? s0 : 0.2f * s0;
        float aexp = expf(s0 * fabsf(eav));

        float scv, ccv; sincosf(0.5f * PI_F * tanhf(eav), &scv, &ccv);
        float mc = c01.x * ccv - c01.y * scv;
        float ms = c01.y * ccv + c01.x * scv;

        float z[4];
        qcirc(mc, ms, c01.z, c01.w, c23.x, c23.y, c23.z, c23.w, qc, z);

        acc0 += aexp * z[0]; acc1 += aexp * z[1];
        acc2 += aexp * z[2]; acc3 += aexp * z[3];
        acc4 += aexp;
    }

#pragma unroll
    for (int m = 1; m < 32; m <<= 1) {
        acc0 += __shfl_xor(acc0, m, 32);
        acc1 += __shfl_xor(acc1, m, 32);
        acc2 += __shfl_xor(acc2, m, 32);
        acc3 += __shfl_xor(acc3, m, 32);
        acc4 += __shfl_xor(acc4, m, 32);
    }

    float dn = acc4 + 1e-8f;
    float v0 = acc0 / dn + hd4.x, v1 = acc1 / dn + hd4.y;
    float v2 = acc2 / dn + hd4.z, v3 = acc3 / dn + hd4.w;
    float mu = 0.25f * (v0 + v1 + v2 + v3);
    float d0 = v0 - mu, d1 = v1 - mu, d2 = v2 - mu, d3 = v3 - mu;
    float var = 0.25f * (d0 * d0 + d1 * d1 + d2 * d2 + d3 * d3);
    float rs = 1.0f / sqrtf(var + 1e-5f);
    float y0 = d0 * rs * g4[0] + be4[0];
    float y1 = d1 * rs * g4[1] + be4[1];
    float y2 = d2 * rs * g4[2] + be4[2];
    float y3 = d3 * rs * g4[3] + be4[3];

    if (FINAL) {
        if (lane == 0)
            out[n] = rb[0] + y0 * rW[0] + y1 * rW[1] + y2 * rW[2] + y3 * rW[3];
    } else {
        y0 = fmaxf(y0, 0.f); y1 = fmaxf(y1, 0.f);
        y2 = fmaxf(y2, 0.f); y3 = fmaxf(y3, 0.f);
        if (lane < 4) {
            float s = pb[lane] + y0 * pW[lane * 4 + 0] + y1 * pW[lane * 4 + 1]
                    + y2 * pW[lane * 4 + 2] + y3 * pW[lane * 4 + 3];
            float hv = (s > 0.f) ? s : expm1f(s);
            float* ob = onrec + (size_t)n * 16;
            float sv, cv; sincosf(0.5f * PI_F * tanhf(hv), &sv, &cv);
            ob[2 * lane]     = cv;
            ob[2 * lane + 1] = sv;
            ob[12 + lane]    = hv;
            float ds = hv * WaN[lane];
            float dd = hv * WaN[4 + lane];
            ds += __shfl_xor(ds, 1); ds += __shfl_xor(ds, 2);
            dd += __shfl_xor(dd, 1); dd += __shfl_xor(dd, 2);
            if (lane == 0) { ob[8] = ds; ohdd[n] = dd; }
        }
    }
}

extern "C" void kernel_launch(void* const* d_in, const int* in_sizes, int n_in,
                              void* d_out, int out_size, void* d_ws, size_t ws_size,
                              hipStream_t stream)
{
    const float* x    = (const float*)d_in[0];
    const int*   ei   = (const int*)d_in[1];
    const float* ea   = (const float*)d_in[2];
    const float* W_ih = (const float*)d_in[3];
    const float* W_hh = (const float*)d_in[4];
    const float* b_ih = (const float*)d_in[5];
    const float* b_hh = (const float*)d_in[6];
    const float* p1W  = (const float*)d_in[7];
    const float* p1b  = (const float*)d_in[8];
    const float* a1W  = (const float*)d_in[9];
    const float* q1w  = (const float*)d_in[10];
    const float* g1   = (const float*)d_in[11];
    const float* be1  = (const float*)d_in[12];
    const float* p2W  = (const float*)d_in[13];
    const float* p2b  = (const float*)d_in[14];
    const float* a2W  = (const float*)d_in[15];
    const float* q2w  = (const float*)d_in[16];
    const float* g2   = (const float*)d_in[17];
    const float* be2  = (const float*)d_in[18];
    const float* rW   = (const float*)d_in[19];
    const float* rb   = (const float*)d_in[20];
    float* out = (float*)d_out;

    int N = in_sizes[0] / 13;
    int E = in_sizes[1] / 2;

    // workspace layout (nrec* 64B-aligned at base)
    float* ws    = (float*)d_ws;
    float* nrec1 = ws;                           // N*16
    float* nrec2 = nrec1 + (size_t)N * 16;       // N*16
    float* hdd1  = nrec2 + (size_t)N * 16;       // N
    float* hdd2  = hdd1 + N;                     // N
    float* qcs   = hdd2 + N;                     // 64 (48 used)
    int* deg  = (int*)(qcs + 64);                // N (zeroed)
    int* off  = deg + N;                         // N
    int* cur  = off + N;                         // N
    int* perm = cur + N;                         // N
    uintptr_t rp = (uintptr_t)(perm + N);
    rp = (rp + 15u) & ~(uintptr_t)15u;           // 16B align
    float2* rec = (float2*)rp;                   // E float2

    hipMemsetAsync(deg, 0, (size_t)N * sizeof(int), stream);

    const int B = 256;
    k_gru<<<(N + 15) / 16, B, 0, stream>>>(x, W_ih, W_hh, b_ih, b_hh, p1W, p1b,
                                           a1W, q1w, q2w, ei, deg, nrec1, hdd1,
                                           qcs, N, E);
    k_scan<<<1, B, 0, stream>>>(deg, off, cur, perm, N);
    k_fill<<<(E + B - 1) / B, B, 0, stream>>>(ei, ea, cur, rec, E);

    // layer 1 -> nrec2/hdd2 (dots use layer-2 attention weights a2W)
    k_qgat<false><<<(N + 7) / 8, B, 0, stream>>>(
        off, deg, perm, rec, nrec1, hdd1, qcs, g1, be1, p2W, p2b, a2W,
        rW, rb, nrec2, hdd2, out, N);

    // layer 2 -> out
    k_qgat<true><<<(N + 7) / 8, B, 0, stream>>>(
        off, deg, perm, rec, nrec2, hdd2, qcs + 24, g2, be2, p2W, p2b, a2W,
        rW, rb, nrec2, hdd2, out, N);
}

// Round 7
// 265.233 us; speedup vs baseline: 1.2985x; 1.1764x over previous
//
#include <hip/hip_runtime.h>
#include <math.h>

// QTGNN: GRU(10 steps, hidden16) -> QGAT layer1 -> QGAT layer2 -> linear head.
// N=10000 nodes, E=320000 edges (+N self loops). All fp32.
// R1: GRU 16 threads/node (shfl matvec) — fixed 256-VGPR spill + 1.7% occupancy.
// R2: fused attention, dropped softmax global-max (shift-invariant up to eps).
// R3: XCD-replica atomics refuted — device atomics RMW at coherence point.
// R4/R5: gather-mode CSR QGAT — killed float atomics (WRITE 50MB->0.5MB).
// R6: coalesced {src,ea} CSR records + 64B node records + split attention dots
//     + degree sort. k_qgat 94->68us, VALUBusy 75%: near-VALU-bound, but
//     node-per-warp wastes ~47% of lanes (deg ~33 on 32 lanes, 2 iters).
// R7: ONE LANE PER EDGE. Wave handles 64 consecutive CSR slots at 100% lane
//     utilization; ballot-driven segmented shfl scan sums equal-dst runs;
//     segment-last lanes atomic (~15K segment atomics total). Node update in
//     a tiny per-node kernel. Degree sort dropped; self-loops are CSR records.
//     Circuit: final RZ layer commutes past trailing CNOT and dies in |.|^2
//     (dropped, -8%); z via unit-norm identity (halved reduction).

#define GH 16
#define SEQ 10
#define PI_F 3.14159265358979323846f

__device__ __forceinline__ float sigmoidf_(float x) { return 1.0f / (1.0f + expf(-x)); }

// ---------------- GRU (16 threads/node) + proj1 + node-record/dot precompute
//                  + fused dst-degree histogram ----------------
__global__ __launch_bounds__(256) void k_gru(
    const float* __restrict__ x, const float* __restrict__ W_ih,
    const float* __restrict__ W_hh, const float* __restrict__ b_ih,
    const float* __restrict__ b_hh, const float* __restrict__ p1W,
    const float* __restrict__ p1b, const float* __restrict__ a1W,
    const float* __restrict__ q1w, const float* __restrict__ q2w,
    const int* __restrict__ ei, int* __restrict__ deg,
    float* __restrict__ nrec1, float* __restrict__ hdd1,
    float* __restrict__ qcs, int N, int E)
{
    // fused degree histogram over edge dst (grid-stride)
    for (int e = blockIdx.x * 256 + threadIdx.x; e < E; e += gridDim.x * 256)
        atomicAdd(&deg[ei[E + e]], 1);

    __shared__ float sW[48 * 16];
    __shared__ float sp1W[4 * 19], sp1b[4];
    for (int i = threadIdx.x; i < 48 * 16; i += 256) sW[i] = W_hh[i];
    if (threadIdx.x < 76) sp1W[threadIdx.x] = p1W[threadIdx.x];
    if (threadIdx.x < 4) sp1b[threadIdx.x] = p1b[threadIdx.x];
    __syncthreads();

    // uniform weight-gate angle table (both layers), once on block 0
    if (blockIdx.x == 0 && threadIdx.x < 12) {
        const float* qw = (threadIdx.x < 6) ? q1w : q2w;
        int rd = threadIdx.x % 6;
        float sy, cy; sincosf(0.5f * qw[rd * 2 + 0], &sy, &cy);
        float sz, cz; sincosf(0.5f * qw[rd * 2 + 1], &sz, &cz);
        float* q = qcs + threadIdx.x * 4;
        q[0] = cy; q[1] = sy; q[2] = cz; q[3] = sz;
    }

    const int j = threadIdx.x & 15;          // hidden unit
    const int n = blockIdx.x * 16 + (threadIdx.x >> 4);
    const bool valid = (n < N);

    float wr[GH], wz[GH], wn[GH];
#pragma unroll
    for (int k = 0; k < GH; ++k) {
        wr[k] = sW[j * 16 + k];
        wz[k] = sW[(16 + j) * 16 + k];
        wn[k] = sW[(32 + j) * 16 + k];
    }
    float wir = W_ih[j], wiz = W_ih[16 + j], win_ = W_ih[32 + j];
    float bir = b_ih[j], biz = b_ih[16 + j], bin_ = b_ih[32 + j];
    float brr = b_hh[j], brz = b_hh[16 + j], brn = b_hh[32 + j];

    float xv[13];
#pragma unroll
    for (int t = 0; t < 13; ++t) xv[t] = valid ? x[n * 13 + t] : 0.f;

    float h = 0.f;
#pragma unroll
    for (int t = 0; t < SEQ; ++t) {
        float xt = xv[t];
        float ghr = brr, ghz = brz, ghn = brn;
#pragma unroll
        for (int k = 0; k < GH; ++k) {
            float hk = __shfl(h, k, 16);
            ghr += wr[k] * hk; ghz += wz[k] * hk; ghn += wn[k] * hk;
        }
        float r  = sigmoidf_(xt * wir + bir + ghr);
        float z  = sigmoidf_(xt * wiz + biz + ghz);
        float nv = tanhf(xt * win_ + bin_ + r * ghn);
        h = (1.f - z) * nv + z * h;
    }

    // proj1: elu([h, x[10:13]] @ p1W.T + p1b) via 16-lane butterfly
    float s0 = h * sp1W[0 * 19 + j];
    float s1 = h * sp1W[1 * 19 + j];
    float s2 = h * sp1W[2 * 19 + j];
    float s3 = h * sp1W[3 * 19 + j];
#pragma unroll
    for (int m = 1; m < 16; m <<= 1) {
        s0 += __shfl_xor(s0, m, 16);
        s1 += __shfl_xor(s1, m, 16);
        s2 += __shfl_xor(s2, m, 16);
        s3 += __shfl_xor(s3, m, 16);
    }
    if (valid && j < 4) {
        float s = (j == 0) ? s0 : (j == 1) ? s1 : (j == 2) ? s2 : s3;
        s += sp1b[j] + xv[10] * sp1W[j * 19 + 16] + xv[11] * sp1W[j * 19 + 17]
           + xv[12] * sp1W[j * 19 + 18];
        float hv = (s > 0.f) ? s : expm1f(s);
        float* nb = nrec1 + (size_t)n * 16;
        float sv, cv; sincosf(0.5f * PI_F * tanhf(hv), &sv, &cv);
        nb[2 * j]     = cv;
        nb[2 * j + 1] = sv;
        nb[12 + j]    = hv;                      // residual copy of h1
        float ds = hv * a1W[j];
        float dd = hv * a1W[4 + j];
        ds += __shfl_xor(ds, 1); ds += __shfl_xor(ds, 2);
        dd += __shfl_xor(dd, 1); dd += __shfl_xor(dd, 2);
        if (j == 0) { nb[8] = ds; hdd1[n] = dd; }
    }
}

// ---------------- offsets (deg+1 incl. self-loop) ----------------
__global__ __launch_bounds__(256) void k_scan(
    const int* __restrict__ deg, int* __restrict__ off,
    int* __restrict__ cur, int N)
{
    __shared__ int part[256];
    const int t = threadIdx.x;
    const int chunk = (N + 255) / 256;
    const int lo = t * chunk;
    const int hi = min(lo + chunk, N);
    int s = 0;
    for (int i = lo; i < hi; ++i) s += deg[i] + 1;
    part[t] = s;
    __syncthreads();
    for (int d = 1; d < 256; d <<= 1) {
        int y = (t >= d) ? part[t - d] : 0;
        __syncthreads();
        part[t] += y;
        __syncthreads();
    }
    int run = part[t] - s;   // exclusive base for this chunk
    for (int i = lo; i < hi; ++i) { off[i] = run; cur[i] = run; run += deg[i] + 1; }
}

// ---------------- CSR fill: {src, ea} records + dst per slot (incl. self-loops) ----------------
__global__ __launch_bounds__(256) void k_fill(
    const int* __restrict__ ei, const float* __restrict__ ea,
    int* __restrict__ cur, float2* __restrict__ rec,
    int* __restrict__ dstv, int E, int N)
{
    int idx = blockIdx.x * 256 + threadIdx.x;
    if (idx >= E + N) return;
    int src, d; float ev;
    if (idx < E) { src = ei[idx]; d = ei[E + idx]; ev = ea[idx]; }
    else         { src = idx - E; d = src;         ev = 1.0f;    }
    int slot = atomicAdd(&cur[d], 1);
    float2 r; r.x = __int_as_float(src); r.y = ev;
    rec[slot] = r;
    dstv[slot] = d;
}

// ---------------- quantum gate helpers (all indices compile-time) ----------------
template <int STR>
__device__ __forceinline__ void ry_g(float (&sr)[16], float (&si)[16], float c, float s) {
#pragma unroll
    for (int i0 = 0; i0 < 16; ++i0) {
        if (i0 & STR) continue;
        int i1 = i0 | STR;
        float a0r = sr[i0], a0i = si[i0], a1r = sr[i1], a1i = si[i1];
        sr[i0] = c * a0r - s * a1r; si[i0] = c * a0i - s * a1i;
        sr[i1] = s * a0r + c * a1r; si[i1] = s * a0i + c * a1i;
    }
}
template <int STR>
__device__ __forceinline__ void rz_g(float (&sr)[16], float (&si)[16], float c, float s) {
#pragma unroll
    for (int i = 0; i < 16; ++i) {
        float r = sr[i], im = si[i];
        if (i & STR) { sr[i] = r * c - im * s; si[i] = im * c + r * s; }
        else         { sr[i] = r * c + im * s; si[i] = im * c - r * s; }
    }
}
template <int SC, int ST>
__device__ __forceinline__ void cnot_g(float (&sr)[16], float (&si)[16]) {
#pragma unroll
    for (int i = 0; i < 16; ++i) {
        if ((i & SC) && !(i & ST)) {
            int j = i | ST;
            float tr = sr[i], ti = si[i];
            sr[i] = sr[j]; si[i] = si[j]; sr[j] = tr; si[j] = ti;
        }
    }
}

// circuit: mc/ms = merged wire-0 half-angle; final RZ layer dropped (pure phase
// past a permutation gate, killed by |.|^2); z via unit-norm identity.
__device__ __forceinline__ void qcirc(
    float mc, float ms, float c1, float s1, float c2, float s2,
    float c3, float s3, const float* __restrict__ qc, float (&z)[4])
{
    float sr[16], si[16];
    // rep 0 input layer on |0000>: product state (real)
    float t0 = mc * c1, t1 = mc * s1, t2 = ms * c1, t3 = ms * s1;
    float u0 = c2 * c3, u1 = c2 * s3, u2 = s2 * c3, u3 = s2 * s3;
    sr[0]  = t0 * u0; sr[1]  = t0 * u1; sr[2]  = t0 * u2; sr[3]  = t0 * u3;
    sr[4]  = t1 * u0; sr[5]  = t1 * u1; sr[6]  = t1 * u2; sr[7]  = t1 * u3;
    sr[8]  = t2 * u0; sr[9]  = t2 * u1; sr[10] = t2 * u2; sr[11] = t2 * u3;
    sr[12] = t3 * u0; sr[13] = t3 * u1; sr[14] = t3 * u2; sr[15] = t3 * u3;
#pragma unroll
    for (int i = 0; i < 16; ++i) si[i] = 0.f;

#pragma unroll
    for (int r = 0; r < 3; ++r) {
        if (r > 0) {  // reps 1,2: input RY layer (wire0 merged with corr)
            ry_g<8>(sr, si, mc, ms);
            ry_g<4>(sr, si, c1, s1);
            ry_g<2>(sr, si, c2, s2);
            ry_g<1>(sr, si, c3, s3);
        }
#pragma unroll
        for (int d = 0; d < 2; ++d) {
            const bool lastd = (r == 2 && d == 1);
            int rd = r * 2 + d;
            float cy = qc[rd * 4 + 0], sy = qc[rd * 4 + 1];
            float cz = qc[rd * 4 + 2], sz = qc[rd * 4 + 3];
            ry_g<8>(sr, si, cy, sy); if (!lastd) rz_g<8>(sr, si, cz, sz);
            ry_g<4>(sr, si, cy, sy); if (!lastd) rz_g<4>(sr, si, cz, sz);
            ry_g<2>(sr, si, cy, sy); if (!lastd) rz_g<2>(sr, si, cz, sz);
            ry_g<1>(sr, si, cy, sy); if (!lastd) rz_g<1>(sr, si, cz, sz);
            if (d == 0) { cnot_g<8, 4>(sr, si); cnot_g<2, 1>(sr, si); }
            else        { cnot_g<4, 2>(sr, si); }
        }
    }

    float p[16];
#pragma unroll
    for (int i = 0; i < 16; ++i) p[i] = sr[i] * sr[i] + si[i] * si[i];
    // z_w = 2 * sum_{i: bit w clear} p[i] - 1   (state norm == 1)
#pragma unroll
    for (int w = 0; w < 4; ++w) {
        const int STR = 8 >> w;
        float zz = 0.f;
#pragma unroll
        for (int i = 0; i < 16; ++i) if (!(i & STR)) zz += p[i];
        z[w] = 2.f * zz - 1.f;
    }
}

// ---------------- edge-parallel QGAT core: 1 lane/edge, segmented wave reduce ----------------
__global__ __launch_bounds__(256) void k_edge(
    const float2* __restrict__ rec, const int* __restrict__ dstv,
    const float* __restrict__ nrec, const float* __restrict__ hdd,
    const float* __restrict__ qcsL, float* __restrict__ S, int EN)
{
    const int slot = blockIdx.x * 256 + threadIdx.x;
    const int lane = threadIdx.x & 63;
    const bool valid = slot < EN;
    int dst = -1;
    float a0 = 0.f, a1 = 0.f, a2 = 0.f, a3 = 0.f, a4 = 0.f;

    if (valid) {
        dst = dstv[slot];
        float2 r = rec[slot];
        int src = __float_as_int(r.x);
        float eav = r.y;
        const float* sb = nrec + (size_t)src * 16;   // one 64B line per src
        float4 c01 = *reinterpret_cast<const float4*>(sb);
        float4 c23 = *reinterpret_cast<const float4*>(sb + 4);
        float s0 = sb[8] + hdd[dst];                 // hsdot[src] + hddot[dst]
        s0 = (s0 > 0.f) ? s0 : 0.2f * s0;
        float aexp = expf(s0 * fabsf(eav));

        float scv, ccv; sincosf(0.5f * PI_F * tanhf(eav), &scv, &ccv);
        float mc = c01.x * ccv - c01.y * scv;
        float ms = c01.y * ccv + c01.x * scv;

        float z[4];
        qcirc(mc, ms, c01.z, c01.w, c23.x, c23.y, c23.z, c23.w, qcsL, z);
        a0 = aexp * z[0]; a1 = aexp * z[1]; a2 = aexp * z[2]; a3 = aexp * z[3];
        a4 = aexp;
    }

    // segmented inclusive scan over equal-dst runs within the wave
    int prevd = __shfl_up(dst, 1);
    bool head = (lane == 0) || (prevd != dst);
    unsigned long long hm = __ballot(head);
    unsigned long long below = (2ull << lane) - 1ull;
    int H = 63 - __clzll((long long)(hm & below));
    int dist = lane - H;
#pragma unroll
    for (int st = 1; st < 64; st <<= 1) {
        float t0 = __shfl_up(a0, st), t1 = __shfl_up(a1, st),
              t2 = __shfl_up(a2, st), t3 = __shfl_up(a3, st),
              t4 = __shfl_up(a4, st);
        if (dist >= st) { a0 += t0; a1 += t1; a2 += t2; a3 += t3; a4 += t4; }
    }
    int nextd = __shfl_down(dst, 1);
    bool lastl = (lane == 63) || (dst != nextd);
    if (lastl && dst >= 0) {
        float* sbase = S + (size_t)dst * 5;
        atomicAdd(sbase + 0, a0); atomicAdd(sbase + 1, a1);
        atomicAdd(sbase + 2, a2); atomicAdd(sbase + 3, a3);
        atomicAdd(sbase + 4, a4);
    }
}

// ---------------- per-node update: norm + residual + LN (+proj2+dots | head) ----------------
template <bool FINAL>
__global__ __launch_bounds__(256) void k_node(
    const float* __restrict__ S, const float* __restrict__ nrec,
    const float* __restrict__ g4, const float* __restrict__ be4,
    const float* __restrict__ pW, const float* __restrict__ pb,
    const float* __restrict__ WaN, const float* __restrict__ rW,
    const float* __restrict__ rb, float* __restrict__ onrec,
    float* __restrict__ ohdd, float* __restrict__ out, int N)
{
    int n = blockIdx.x * 256 + threadIdx.x;
    if (n >= N) return;
    const float* sb = S + (size_t)n * 5;
    const float* nb = nrec + (size_t)n * 16;
    float dn = sb[4] + 1e-8f;
    float v0 = sb[0] / dn + nb[12];
    float v1 = sb[1] / dn + nb[13];
    float v2 = sb[2] / dn + nb[14];
    float v3 = sb[3] / dn + nb[15];
    float mu = 0.25f * (v0 + v1 + v2 + v3);
    float d0 = v0 - mu, d1 = v1 - mu, d2 = v2 - mu, d3 = v3 - mu;
    float var = 0.25f * (d0 * d0 + d1 * d1 + d2 * d2 + d3 * d3);
    float rs = 1.0f / sqrtf(var + 1e-5f);
    float y0 = d0 * rs * g4[0] + be4[0];
    float y1 = d1 * rs * g4[1] + be4[1];
    float y2 = d2 * rs * g4[2] + be4[2];
    float y3 = d3 * rs * g4[3] + be4[3];

    if (FINAL) {
        out[n] = rb[0] + y0 * rW[0] + y1 * rW[1] + y2 * rW[2] + y3 * rW[3];
    } else {
        y0 = fmaxf(y0, 0.f); y1 = fmaxf(y1, 0.f);
        y2 = fmaxf(y2, 0.f); y3 = fmaxf(y3, 0.f);
        float hv[4];
#pragma unroll
        for (int w = 0; w < 4; ++w) {
            float s = pb[w] + y0 * pW[w * 4 + 0] + y1 * pW[w * 4 + 1]
                    + y2 * pW[w * 4 + 2] + y3 * pW[w * 4 + 3];
            hv[w] = (s > 0.f) ? s : expm1f(s);
        }
        float* ob = onrec + (size_t)n * 16;
        float ds = 0.f, dd = 0.f;
#pragma unroll
        for (int w = 0; w < 4; ++w) {
            float sv, cv; sincosf(0.5f * PI_F * tanhf(hv[w]), &sv, &cv);
            ob[2 * w]     = cv;
            ob[2 * w + 1] = sv;
            ob[12 + w]    = hv[w];
            ds += hv[w] * WaN[w];
            dd += hv[w] * WaN[4 + w];
        }
        ob[8] = ds;
        ohdd[n] = dd;
    }
}

extern "C" void kernel_launch(void* const* d_in, const int* in_sizes, int n_in,
                              void* d_out, int out_size, void* d_ws, size_t ws_size,
                              hipStream_t stream)
{
    const float* x    = (const float*)d_in[0];
    const int*   ei   = (const int*)d_in[1];
    const float* ea   = (const float*)d_in[2];
    const float* W_ih = (const float*)d_in[3];
    const float* W_hh = (const float*)d_in[4];
    const float* b_ih = (const float*)d_in[5];
    const float* b_hh = (const float*)d_in[6];
    const float* p1W  = (const float*)d_in[7];
    const float* p1b  = (const float*)d_in[8];
    const float* a1W  = (const float*)d_in[9];
    const float* q1w  = (const float*)d_in[10];
    const float* g1   = (const float*)d_in[11];
    const float* be1  = (const float*)d_in[12];
    const float* p2W  = (const float*)d_in[13];
    const float* p2b  = (const float*)d_in[14];
    const float* a2W  = (const float*)d_in[15];
    const float* q2w  = (const float*)d_in[16];
    const float* g2   = (const float*)d_in[17];
    const float* be2  = (const float*)d_in[18];
    const float* rW   = (const float*)d_in[19];
    const float* rb   = (const float*)d_in[20];
    float* out = (float*)d_out;

    int N  = in_sizes[0] / 13;
    int E  = in_sizes[1] / 2;
    int EN = E + N;

    // workspace layout
    float* ws    = (float*)d_ws;
    float* nrec1 = ws;                           // N*16
    float* nrec2 = nrec1 + (size_t)N * 16;       // N*16
    float* hdd1  = nrec2 + (size_t)N * 16;       // N
    float* hdd2  = hdd1 + N;                     // N
    float* qcs   = hdd2 + N;                     // 64 (48 used)
    float* S1    = qcs + 64;                     // N*5 (zeroed)
    float* S2    = S1 + (size_t)N * 5;           // N*5 (zeroed)
    int* deg  = (int*)(S2 + (size_t)N * 5);      // N   (zeroed)
    int* off  = deg + N;                         // N
    int* cur  = off + N;                         // N
    int* dstv = cur + N;                         // EN
    uintptr_t rp = (uintptr_t)(dstv + EN);
    rp = (rp + 15u) & ~(uintptr_t)15u;           // 16B align
    float2* rec = (float2*)rp;                   // EN float2

    // zero S1,S2,deg in one shot (contiguous)
    hipMemsetAsync(S1, 0, ((size_t)N * 10 + N) * sizeof(float), stream);

    const int B = 256;
    k_gru<<<(N + 15) / 16, B, 0, stream>>>(x, W_ih, W_hh, b_ih, b_hh, p1W, p1b,
                                           a1W, q1w, q2w, ei, deg, nrec1, hdd1,
                                           qcs, N, E);
    k_scan<<<1, B, 0, stream>>>(deg, off, cur, N);
    k_fill<<<(EN + B - 1) / B, B, 0, stream>>>(ei, ea, cur, rec, dstv, E, N);

    // layer 1
    k_edge<<<(EN + B - 1) / B, B, 0, stream>>>(rec, dstv, nrec1, hdd1, qcs, S1, EN);
    k_node<false><<<(N + B - 1) / B, B, 0, stream>>>(
        S1, nrec1, g1, be1, p2W, p2b, a2W, rW, rb, nrec2, hdd2, out, N);

    // layer 2
    k_edge<<<(EN + B - 1) / B, B, 0, stream>>>(rec, dstv, nrec2, hdd2, qcs + 24, S2, EN);
    k_node<true><<<(N + B - 1) / B, B, 0, stream>>>(
        S2, nrec2, g2, be2, p2W, p2b, a2W, rW, rb, nrec2, hdd2, out, N);
}

// Round 8
// 257.246 us; speedup vs baseline: 1.3388x; 1.0310x over previous
//
#include <hip/hip_runtime.h>
#include <math.h>

// QTGNN: GRU(10 steps, hidden16) -> QGAT layer1 -> QGAT layer2 -> linear head.
// N=10000 nodes, E=320000 edges (+N self loops). All fp32.
// R1: GRU 16 threads/node (shfl matvec) — fixed 256-VGPR spill + 1.7% occupancy.
// R2: fused attention, dropped softmax global-max (shift-invariant up to eps).
// R3: XCD-replica atomics refuted — device atomics RMW at coherence point.
// R4/R5: gather-mode CSR QGAT — killed float atomics (WRITE 50MB->0.5MB).
// R6: coalesced CSR records + 64B node records + split attention dots.
// R7: 1 lane/edge + ballot-segmented shfl scan; k_edge 68->46.6us, VALU 60%.
// R8: k_edge was latency-exposed (2 dependent scatter rounds per edge, nothing
//     to overlap). Now 2 edges/thread: all of edge B's loads issue before edge
//     A's ~7000-cycle circuit -> B latency fully hidden. Per-edge tanh/sincos
//     hoisted into k_fill (once per edge, not per edge per layer); rec=float4
//     {src,dst,ccv,scv}+|ea| kills the dstv load. S zeroing moved into k_gru
//     (memset = deg only). k_scan widened to 1024 threads.

#define GH 16
#define SEQ 10
#define PI_F 3.14159265358979323846f

__device__ __forceinline__ float sigmoidf_(float x) { return 1.0f / (1.0f + expf(-x)); }

// ---------------- GRU (16 threads/node) + proj1 + node-record/dot precompute
//                  + fused dst-degree histogram + S zeroing ----------------
__global__ __launch_bounds__(256) void k_gru(
    const float* __restrict__ x, const float* __restrict__ W_ih,
    const float* __restrict__ W_hh, const float* __restrict__ b_ih,
    const float* __restrict__ b_hh, const float* __restrict__ p1W,
    const float* __restrict__ p1b, const float* __restrict__ a1W,
    const float* __restrict__ q1w, const float* __restrict__ q2w,
    const int* __restrict__ ei, int* __restrict__ deg,
    float* __restrict__ nrec1, float* __restrict__ hdd1,
    float* __restrict__ qcs, float* __restrict__ Sz, int N, int E)
{
    // zero the S accumulators (S1,S2 contiguous: N*10 floats)
    for (int i = blockIdx.x * 256 + threadIdx.x; i < N * 10; i += gridDim.x * 256)
        Sz[i] = 0.f;
    // fused degree histogram over edge dst (grid-stride)
    for (int e = blockIdx.x * 256 + threadIdx.x; e < E; e += gridDim.x * 256)
        atomicAdd(&deg[ei[E + e]], 1);

    __shared__ float sW[48 * 16];
    __shared__ float sp1W[4 * 19], sp1b[4];
    for (int i = threadIdx.x; i < 48 * 16; i += 256) sW[i] = W_hh[i];
    if (threadIdx.x < 76) sp1W[threadIdx.x] = p1W[threadIdx.x];
    if (threadIdx.x < 4) sp1b[threadIdx.x] = p1b[threadIdx.x];
    __syncthreads();

    // uniform weight-gate angle table (both layers), once on block 0
    if (blockIdx.x == 0 && threadIdx.x < 12) {
        const float* qw = (threadIdx.x < 6) ? q1w : q2w;
        int rd = threadIdx.x % 6;
        float sy, cy; sincosf(0.5f * qw[rd * 2 + 0], &sy, &cy);
        float sz, cz; sincosf(0.5f * qw[rd * 2 + 1], &sz, &cz);
        float* q = qcs + threadIdx.x * 4;
        q[0] = cy; q[1] = sy; q[2] = cz; q[3] = sz;
    }

    const int j = threadIdx.x & 15;          // hidden unit
    const int n = blockIdx.x * 16 + (threadIdx.x >> 4);
    const bool valid = (n < N);

    float wr[GH], wz[GH], wn[GH];
#pragma unroll
    for (int k = 0; k < GH; ++k) {
        wr[k] = sW[j * 16 + k];
        wz[k] = sW[(16 + j) * 16 + k];
        wn[k] = sW[(32 + j) * 16 + k];
    }
    float wir = W_ih[j], wiz = W_ih[16 + j], win_ = W_ih[32 + j];
    float bir = b_ih[j], biz = b_ih[16 + j], bin_ = b_ih[32 + j];
    float brr = b_hh[j], brz = b_hh[16 + j], brn = b_hh[32 + j];

    float xv[13];
#pragma unroll
    for (int t = 0; t < 13; ++t) xv[t] = valid ? x[n * 13 + t] : 0.f;

    float h = 0.f;
#pragma unroll
    for (int t = 0; t < SEQ; ++t) {
        float xt = xv[t];
        float ghr = brr, ghz = brz, ghn = brn;
#pragma unroll
        for (int k = 0; k < GH; ++k) {
            float hk = __shfl(h, k, 16);
            ghr += wr[k] * hk; ghz += wz[k] * hk; ghn += wn[k] * hk;
        }
        float r  = sigmoidf_(xt * wir + bir + ghr);
        float z  = sigmoidf_(xt * wiz + biz + ghz);
        float nv = tanhf(xt * win_ + bin_ + r * ghn);
        h = (1.f - z) * nv + z * h;
    }

    // proj1: elu([h, x[10:13]] @ p1W.T + p1b) via 16-lane butterfly
    float s0 = h * sp1W[0 * 19 + j];
    float s1 = h * sp1W[1 * 19 + j];
    float s2 = h * sp1W[2 * 19 + j];
    float s3 = h * sp1W[3 * 19 + j];
#pragma unroll
    for (int m = 1; m < 16; m <<= 1) {
        s0 += __shfl_xor(s0, m, 16);
        s1 += __shfl_xor(s1, m, 16);
        s2 += __shfl_xor(s2, m, 16);
        s3 += __shfl_xor(s3, m, 16);
    }
    if (valid && j < 4) {
        float s = (j == 0) ? s0 : (j == 1) ? s1 : (j == 2) ? s2 : s3;
        s += sp1b[j] + xv[10] * sp1W[j * 19 + 16] + xv[11] * sp1W[j * 19 + 17]
           + xv[12] * sp1W[j * 19 + 18];
        float hv = (s > 0.f) ? s : expm1f(s);
        float* nb = nrec1 + (size_t)n * 16;
        float sv, cv; sincosf(0.5f * PI_F * tanhf(hv), &sv, &cv);
        nb[2 * j]     = cv;
        nb[2 * j + 1] = sv;
        nb[12 + j]    = hv;                      // residual copy of h1
        float ds = hv * a1W[j];
        float dd = hv * a1W[4 + j];
        ds += __shfl_xor(ds, 1); ds += __shfl_xor(ds, 2);
        dd += __shfl_xor(dd, 1); dd += __shfl_xor(dd, 2);
        if (j == 0) { nb[8] = ds; hdd1[n] = dd; }
    }
}

// ---------------- offsets (deg+1 incl. self-loop), 1024-thread scan ----------------
__global__ __launch_bounds__(1024) void k_scan(
    const int* __restrict__ deg, int* __restrict__ off,
    int* __restrict__ cur, int N)
{
    __shared__ int part[1024];
    const int t = threadIdx.x;
    const int chunk = (N + 1023) / 1024;
    const int lo = t * chunk;
    const int hi = min(lo + chunk, N);
    int s = 0;
    for (int i = lo; i < hi; ++i) s += deg[i] + 1;
    part[t] = s;
    __syncthreads();
    for (int d = 1; d < 1024; d <<= 1) {
        int y = (t >= d) ? part[t - d] : 0;
        __syncthreads();
        part[t] += y;
        __syncthreads();
    }
    int run = part[t] - s;   // exclusive base for this chunk
    for (int i = lo; i < hi; ++i) { off[i] = run; cur[i] = run; run += deg[i] + 1; }
}

// ---------------- CSR fill: {src, dst, cos, sin} + |ea| (incl. self-loops) ----------------
__global__ __launch_bounds__(256) void k_fill(
    const int* __restrict__ ei, const float* __restrict__ ea,
    int* __restrict__ cur, float4* __restrict__ rec,
    float* __restrict__ aeav, int E, int N)
{
    int idx = blockIdx.x * 256 + threadIdx.x;
    if (idx >= E + N) return;
    int src, d; float ev;
    if (idx < E) { src = ei[idx]; d = ei[E + idx]; ev = ea[idx]; }
    else         { src = idx - E; d = src;         ev = 1.0f;    }
    int slot = atomicAdd(&cur[d], 1);
    float scv, ccv; sincosf(0.5f * PI_F * tanhf(ev), &scv, &ccv);
    float4 r;
    r.x = __int_as_float(src); r.y = __int_as_float(d);
    r.z = ccv; r.w = scv;
    rec[slot] = r;
    aeav[slot] = fabsf(ev);
}

// ---------------- quantum gate helpers (all indices compile-time) ----------------
template <int STR>
__device__ __forceinline__ void ry_g(float (&sr)[16], float (&si)[16], float c, float s) {
#pragma unroll
    for (int i0 = 0; i0 < 16; ++i0) {
        if (i0 & STR) continue;
        int i1 = i0 | STR;
        float a0r = sr[i0], a0i = si[i0], a1r = sr[i1], a1i = si[i1];
        sr[i0] = c * a0r - s * a1r; si[i0] = c * a0i - s * a1i;
        sr[i1] = s * a0r + c * a1r; si[i1] = s * a0i + c * a1i;
    }
}
template <int STR>
__device__ __forceinline__ void rz_g(float (&sr)[16], float (&si)[16], float c, float s) {
#pragma unroll
    for (int i = 0; i < 16; ++i) {
        float r = sr[i], im = si[i];
        if (i & STR) { sr[i] = r * c - im * s; si[i] = im * c + r * s; }
        else         { sr[i] = r * c + im * s; si[i] = im * c - r * s; }
    }
}
template <int SC, int ST>
__device__ __forceinline__ void cnot_g(float (&sr)[16], float (&si)[16]) {
#pragma unroll
    for (int i = 0; i < 16; ++i) {
        if ((i & SC) && !(i & ST)) {
            int j = i | ST;
            float tr = sr[i], ti = si[i];
            sr[i] = sr[j]; si[i] = si[j]; sr[j] = tr; si[j] = ti;
        }
    }
}

// circuit: mc/ms = merged wire-0 half-angle; final RZ layer dropped (pure phase
// past a permutation gate, killed by |.|^2); z via unit-norm identity.
__device__ __forceinline__ void qcirc(
    float mc, float ms, float c1, float s1, float c2, float s2,
    float c3, float s3, const float* __restrict__ qc, float (&z)[4])
{
    float sr[16], si[16];
    // rep 0 input layer on |0000>: product state (real)
    float t0 = mc * c1, t1 = mc * s1, t2 = ms * c1, t3 = ms * s1;
    float u0 = c2 * c3, u1 = c2 * s3, u2 = s2 * c3, u3 = s2 * s3;
    sr[0]  = t0 * u0; sr[1]  = t0 * u1; sr[2]  = t0 * u2; sr[3]  = t0 * u3;
    sr[4]  = t1 * u0; sr[5]  = t1 * u1; sr[6]  = t1 * u2; sr[7]  = t1 * u3;
    sr[8]  = t2 * u0; sr[9]  = t2 * u1; sr[10] = t2 * u2; sr[11] = t2 * u3;
    sr[12] = t3 * u0; sr[13] = t3 * u1; sr[14] = t3 * u2; sr[15] = t3 * u3;
#pragma unroll
    for (int i = 0; i < 16; ++i) si[i] = 0.f;

#pragma unroll
    for (int r = 0; r < 3; ++r) {
        if (r > 0) {  // reps 1,2: input RY layer (wire0 merged with corr)
            ry_g<8>(sr, si, mc, ms);
            ry_g<4>(sr, si, c1, s1);
            ry_g<2>(sr, si, c2, s2);
            ry_g<1>(sr, si, c3, s3);
        }
#pragma unroll
        for (int d = 0; d < 2; ++d) {
            const bool lastd = (r == 2 && d == 1);
            int rd = r * 2 + d;
            float cy = qc[rd * 4 + 0], sy = qc[rd * 4 + 1];
            float cz = qc[rd * 4 + 2], sz = qc[rd * 4 + 3];
            ry_g<8>(sr, si, cy, sy); if (!lastd) rz_g<8>(sr, si, cz, sz);
            ry_g<4>(sr, si, cy, sy); if (!lastd) rz_g<4>(sr, si, cz, sz);
            ry_g<2>(sr, si, cy, sy); if (!lastd) rz_g<2>(sr, si, cz, sz);
            ry_g<1>(sr, si, cy, sy); if (!lastd) rz_g<1>(sr, si, cz, sz);
            if (d == 0) { cnot_g<8, 4>(sr, si); cnot_g<2, 1>(sr, si); }
            else        { cnot_g<4, 2>(sr, si); }
        }
    }

    float p[16];
#pragma unroll
    for (int i = 0; i < 16; ++i) p[i] = sr[i] * sr[i] + si[i] * si[i];
    // z_w = 2 * sum_{i: bit w clear} p[i] - 1   (state norm == 1)
#pragma unroll
    for (int w = 0; w < 4; ++w) {
        const int STR = 8 >> w;
        float zz = 0.f;
#pragma unroll
        for (int i = 0; i < 16; ++i) if (!(i & STR)) zz += p[i];
        z[w] = 2.f * zz - 1.f;
    }
}

// segmented wave reduce over equal-dst runs + atomic by segment-last lane
__device__ __forceinline__ void segreduce(
    int dst, int lane, float a0, float a1, float a2, float a3, float a4,
    float* __restrict__ S)
{
    int prevd = __shfl_up(dst, 1);
    bool head = (lane == 0) || (prevd != dst);
    unsigned long long hm = __ballot(head);
    unsigned long long below = (2ull << lane) - 1ull;
    int H = 63 - __clzll((long long)(hm & below));
    int dist = lane - H;
#pragma unroll
    for (int st = 1; st < 64; st <<= 1) {
        float t0 = __shfl_up(a0, st), t1 = __shfl_up(a1, st),
              t2 = __shfl_up(a2, st), t3 = __shfl_up(a3, st),
              t4 = __shfl_up(a4, st);
        if (dist >= st) { a0 += t0; a1 += t1; a2 += t2; a3 += t3; a4 += t4; }
    }
    int nextd = __shfl_down(dst, 1);
    bool lastl = (lane == 63) || (dst != nextd);
    if (lastl && dst >= 0) {
        float* sbase = S + (size_t)dst * 5;
        atomicAdd(sbase + 0, a0); atomicAdd(sbase + 1, a1);
        atomicAdd(sbase + 2, a2); atomicAdd(sbase + 3, a3);
        atomicAdd(sbase + 4, a4);
    }
}

// ---------------- edge-parallel QGAT: 2 edges/thread, B loads prefetched under A compute ----------------
__global__ __launch_bounds__(256) void k_edge(
    const float4* __restrict__ rec, const float* __restrict__ aeav,
    const float* __restrict__ nrec, const float* __restrict__ hdd,
    const float* __restrict__ qcsL, float* __restrict__ S, int EN, int G)
{
    const int g = blockIdx.x * 256 + threadIdx.x;
    const int lane = threadIdx.x & 63;
    const int sA = g, sB = g + G;
    const bool vA = sA < EN, vB = sB < EN;

    // ---- issue ALL loads for both edges up front ----
    float4 rA = vA ? rec[sA] : make_float4(0.f, 0.f, 1.f, 0.f);
    float4 rB = vB ? rec[sB] : make_float4(0.f, 0.f, 1.f, 0.f);
    float aeA = vA ? aeav[sA] : 0.f;
    float aeB = vB ? aeav[sB] : 0.f;
    int srcA = __float_as_int(rA.x), dstA = vA ? __float_as_int(rA.y) : -1;
    int srcB = __float_as_int(rB.x), dstB = vB ? __float_as_int(rB.y) : -1;
    const float* sbA = nrec + (size_t)(vA ? srcA : 0) * 16;
    const float* sbB = nrec + (size_t)(vB ? srcB : 0) * 16;
    float4 c01A = *reinterpret_cast<const float4*>(sbA);
    float4 c23A = *reinterpret_cast<const float4*>(sbA + 4);
    float hsA = sbA[8];
    float hdA = hdd[vA ? dstA : 0];
    float4 c01B = *reinterpret_cast<const float4*>(sbB);
    float4 c23B = *reinterpret_cast<const float4*>(sbB + 4);
    float hsB = sbB[8];
    float hdB = hdd[vB ? dstB : 0];

    // ---- edge A: attention + circuit (B loads in flight) ----
    float a0 = 0.f, a1 = 0.f, a2 = 0.f, a3 = 0.f, a4 = 0.f;
    if (vA) {
        float s0 = hsA + hdA;
        s0 = (s0 > 0.f) ? s0 : 0.2f * s0;
        float aexp = expf(s0 * aeA);
        float mc = c01A.x * rA.z - c01A.y * rA.w;
        float ms = c01A.y * rA.z + c01A.x * rA.w;
        float z[4];
        qcirc(mc, ms, c01A.z, c01A.w, c23A.x, c23A.y, c23A.z, c23A.w, qcsL, z);
        a0 = aexp * z[0]; a1 = aexp * z[1]; a2 = aexp * z[2]; a3 = aexp * z[3];
        a4 = aexp;
    }
    segreduce(dstA, lane, a0, a1, a2, a3, a4, S);

    // ---- edge B ----
    a0 = a1 = a2 = a3 = a4 = 0.f;
    if (vB) {
        float s0 = hsB + hdB;
        s0 = (s0 > 0.f) ? s0 : 0.2f * s0;
        float aexp = expf(s0 * aeB);
        float mc = c01B.x * rB.z - c01B.y * rB.w;
        float ms = c01B.y * rB.z + c01B.x * rB.w;
        float z[4];
        qcirc(mc, ms, c01B.z, c01B.w, c23B.x, c23B.y, c23B.z, c23B.w, qcsL, z);
        a0 = aexp * z[0]; a1 = aexp * z[1]; a2 = aexp * z[2]; a3 = aexp * z[3];
        a4 = aexp;
    }
    segreduce(dstB, lane, a0, a1, a2, a3, a4, S);
}

// ---------------- per-node update: norm + residual + LN (+proj2+dots | head) ----------------
template <bool FINAL>
__global__ __launch_bounds__(256) void k_node(
    const float* __restrict__ S, const float* __restrict__ nrec,
    const float* __restrict__ g4, const float* __restrict__ be4,
    const float* __restrict__ pW, const float* __restrict__ pb,
    const float* __restrict__ WaN, const float* __restrict__ rW,
    const float* __restrict__ rb, float* __restrict__ onrec,
    float* __restrict__ ohdd, float* __restrict__ out, int N)
{
    int n = blockIdx.x * 256 + threadIdx.x;
    if (n >= N) return;
    const float* sb = S + (size_t)n * 5;
    const float* nb = nrec + (size_t)n * 16;
    float dn = sb[4] + 1e-8f;
    float v0 = sb[0] / dn + nb[12];
    float v1 = sb[1] / dn + nb[13];
    float v2 = sb[2] / dn + nb[14];
    float v3 = sb[3] / dn + nb[15];
    float mu = 0.25f * (v0 + v1 + v2 + v3);
    float d0 = v0 - mu, d1 = v1 - mu, d2 = v2 - mu, d3 = v3 - mu;
    float var = 0.25f * (d0 * d0 + d1 * d1 + d2 * d2 + d3 * d3);
    float rs = 1.0f / sqrtf(var + 1e-5f);
    float y0 = d0 * rs * g4[0] + be4[0];
    float y1 = d1 * rs * g4[1] + be4[1];
    float y2 = d2 * rs * g4[2] + be4[2];
    float y3 = d3 * rs * g4[3] + be4[3];

    if (FINAL) {
        out[n] = rb[0] + y0 * rW[0] + y1 * rW[1] + y2 * rW[2] + y3 * rW[3];
    } else {
        y0 = fmaxf(y0, 0.f); y1 = fmaxf(y1, 0.f);
        y2 = fmaxf(y2, 0.f); y3 = fmaxf(y3, 0.f);
        float hv[4];
#pragma unroll
        for (int w = 0; w < 4; ++w) {
            float s = pb[w] + y0 * pW[w * 4 + 0] + y1 * pW[w * 4 + 1]
                    + y2 * pW[w * 4 + 2] + y3 * pW[w * 4 + 3];
            hv[w] = (s > 0.f) ? s : expm1f(s);
        }
        float* ob = onrec + (size_t)n * 16;
        float ds = 0.f, dd = 0.f;
#pragma unroll
        for (int w = 0; w < 4; ++w) {
            float sv, cv; sincosf(0.5f * PI_F * tanhf(hv[w]), &sv, &cv);
            ob[2 * w]     = cv;
            ob[2 * w + 1] = sv;
            ob[12 + w]    = hv[w];
            ds += hv[w] * WaN[w];
            dd += hv[w] * WaN[4 + w];
        }
        ob[8] = ds;
        ohdd[n] = dd;
    }
}

extern "C" void kernel_launch(void* const* d_in, const int* in_sizes, int n_in,
                              void* d_out, int out_size, void* d_ws, size_t ws_size,
                              hipStream_t stream)
{
    const float* x    = (const float*)d_in[0];
    const int*   ei   = (const int*)d_in[1];
    const float* ea   = (const float*)d_in[2];
    const float* W_ih = (const float*)d_in[3];
    const float* W_hh = (const float*)d_in[4];
    const float* b_ih = (const float*)d_in[5];
    const float* b_hh = (const float*)d_in[6];
    const float* p1W  = (const float*)d_in[7];
    const float* p1b  = (const float*)d_in[8];
    const float* a1W  = (const float*)d_in[9];
    const float* q1w  = (const float*)d_in[10];
    const float* g1   = (const float*)d_in[11];
    const float* be1  = (const float*)d_in[12];
    const float* p2W  = (const float*)d_in[13];
    const float* p2b  = (const float*)d_in[14];
    const float* a2W  = (const float*)d_in[15];
    const float* q2w  = (const float*)d_in[16];
    const float* g2   = (const float*)d_in[17];
    const float* be2  = (const float*)d_in[18];
    const float* rW   = (const float*)d_in[19];
    const float* rb   = (const float*)d_in[20];
    float* out = (float*)d_out;

    int N  = in_sizes[0] / 13;
    int E  = in_sizes[1] / 2;
    int EN = E + N;

    // workspace layout
    float* ws    = (float*)d_ws;
    float* nrec1 = ws;                           // N*16
    float* nrec2 = nrec1 + (size_t)N * 16;       // N*16
    float* hdd1  = nrec2 + (size_t)N * 16;       // N
    float* hdd2  = hdd1 + N;                     // N
    float* qcs   = hdd2 + N;                     // 64 (48 used)
    float* S1    = qcs + 64;                     // N*5 (zeroed in k_gru)
    float* S2    = S1 + (size_t)N * 5;           // N*5 (zeroed in k_gru)
    float* aeav  = S2 + (size_t)N * 5;           // EN
    int* deg  = (int*)(aeav + EN);               // N   (memset)
    int* off  = deg + N;                         // N
    int* cur  = off + N;                         // N
    uintptr_t rp = (uintptr_t)(cur + N);
    rp = (rp + 15u) & ~(uintptr_t)15u;           // 16B align
    float4* rec = (float4*)rp;                   // EN float4

    hipMemsetAsync(deg, 0, (size_t)N * sizeof(int), stream);

    const int B = 256;
    k_gru<<<(N + 15) / 16, B, 0, stream>>>(x, W_ih, W_hh, b_ih, b_hh, p1W, p1b,
                                           a1W, q1w, q2w, ei, deg, nrec1, hdd1,
                                           qcs, S1, N, E);
    k_scan<<<1, 1024, 0, stream>>>(deg, off, cur, N);
    k_fill<<<(EN + B - 1) / B, B, 0, stream>>>(ei, ea, cur, rec, aeav, E, N);

    // 2 edges/thread
    int half = (EN + 1) / 2;
    int eblocks = (half + B - 1) / B;
    int G = eblocks * B;

    // layer 1
    k_edge<<<eblocks, B, 0, stream>>>(rec, aeav, nrec1, hdd1, qcs, S1, EN, G);
    k_node<false><<<(N + B - 1) / B, B, 0, stream>>>(
        S1, nrec1, g1, be1, p2W, p2b, a2W, rW, rb, nrec2, hdd2, out, N);

    // layer 2
    k_edge<<<eblocks, B, 0, stream>>>(rec, aeav, nrec2, hdd2, qcs + 24, S2, EN, G);
    k_node<true><<<(N + B - 1) / B, B, 0, stream>>>(
        S2, nrec2, g2, be2, p2W, p2b, a2W, rW, rb, nrec2, hdd2, out, N);
}

// Round 9
// 238.321 us; speedup vs baseline: 1.4451x; 1.0794x over previous
//
#include <hip/hip_runtime.h>
#include <math.h>

// QTGNN: GRU(10 steps, hidden16) -> QGAT layer1 -> QGAT layer2 -> linear head.
// N=10000 nodes, E=320000 edges (+N self loops). All fp32.
// R1: GRU 16 threads/node (shfl matvec).
// R2: fused attention, dropped softmax global-max (shift-invariant up to eps).
// R3: XCD-replica atomics refuted — device atomics RMW at coherence point.
// R4-R6: gather CSR + coalesced records + split attention dots.
// R7: 1 lane/edge + segmented shfl scan (46.6us/layer, VALU 60%).
// R8: 2-edge prefetch REGRESSED (48.6us, TLP loss > ILP gain). Reverted.
// R9: per-edge circuit ELIMINATED. psi = G2 U G1 U G0 U e0 with U =
//     (mc I + ms K) R123; binomial expansion in (mc,ms) collapses by K-count:
//     psi = mc^3 v0 + mc^2 ms v1 + mc ms^2 v2 + ms^3 v3 (v_k per-src).
//     z_w = c^T M^w c with M^w per-src 4x4 symmetric (40 floats/node).
//     k_gmat builds G_r numerically from the validated gate helpers;
//     k_prep (16 lanes/node) builds M^w via shfl-matvecs + 16-lane WHT;
//     k_edge is now ~100 VALU + 11 float4 L2 gathers per edge.

#define GH 16
#define SEQ 10
#define PI_F 3.14159265358979323846f

__device__ __forceinline__ float sigmoidf_(float x) { return 1.0f / (1.0f + expf(-x)); }

// ---------------- GRU (16 threads/node) + proj1 + node-record/dot precompute
//                  + fused dst-degree histogram + S zeroing ----------------
__global__ __launch_bounds__(256) void k_gru(
    const float* __restrict__ x, const float* __restrict__ W_ih,
    const float* __restrict__ W_hh, const float* __restrict__ b_ih,
    const float* __restrict__ b_hh, const float* __restrict__ p1W,
    const float* __restrict__ p1b, const float* __restrict__ a1W,
    const int* __restrict__ ei, int* __restrict__ deg,
    float* __restrict__ nrec1, float* __restrict__ hdd1,
    float* __restrict__ Sz, int N, int E)
{
    for (int i = blockIdx.x * 256 + threadIdx.x; i < N * 10; i += gridDim.x * 256)
        Sz[i] = 0.f;
    for (int e = blockIdx.x * 256 + threadIdx.x; e < E; e += gridDim.x * 256)
        atomicAdd(&deg[ei[E + e]], 1);

    __shared__ float sW[48 * 16];
    __shared__ float sp1W[4 * 19], sp1b[4];
    for (int i = threadIdx.x; i < 48 * 16; i += 256) sW[i] = W_hh[i];
    if (threadIdx.x < 76) sp1W[threadIdx.x] = p1W[threadIdx.x];
    if (threadIdx.x < 4) sp1b[threadIdx.x] = p1b[threadIdx.x];
    __syncthreads();

    const int j = threadIdx.x & 15;
    const int n = blockIdx.x * 16 + (threadIdx.x >> 4);
    const bool valid = (n < N);

    float wr[GH], wz[GH], wn[GH];
#pragma unroll
    for (int k = 0; k < GH; ++k) {
        wr[k] = sW[j * 16 + k];
        wz[k] = sW[(16 + j) * 16 + k];
        wn[k] = sW[(32 + j) * 16 + k];
    }
    float wir = W_ih[j], wiz = W_ih[16 + j], win_ = W_ih[32 + j];
    float bir = b_ih[j], biz = b_ih[16 + j], bin_ = b_ih[32 + j];
    float brr = b_hh[j], brz = b_hh[16 + j], brn = b_hh[32 + j];

    float xv[13];
#pragma unroll
    for (int t = 0; t < 13; ++t) xv[t] = valid ? x[n * 13 + t] : 0.f;

    float h = 0.f;
#pragma unroll
    for (int t = 0; t < SEQ; ++t) {
        float xt = xv[t];
        float ghr = brr, ghz = brz, ghn = brn;
#pragma unroll
        for (int k = 0; k < GH; ++k) {
            float hk = __shfl(h, k, 16);
            ghr += wr[k] * hk; ghz += wz[k] * hk; ghn += wn[k] * hk;
        }
        float r  = sigmoidf_(xt * wir + bir + ghr);
        float z  = sigmoidf_(xt * wiz + biz + ghz);
        float nv = tanhf(xt * win_ + bin_ + r * ghn);
        h = (1.f - z) * nv + z * h;
    }

    float s0 = h * sp1W[0 * 19 + j];
    float s1 = h * sp1W[1 * 19 + j];
    float s2 = h * sp1W[2 * 19 + j];
    float s3 = h * sp1W[3 * 19 + j];
#pragma unroll
    for (int m = 1; m < 16; m <<= 1) {
        s0 += __shfl_xor(s0, m, 16);
        s1 += __shfl_xor(s1, m, 16);
        s2 += __shfl_xor(s2, m, 16);
        s3 += __shfl_xor(s3, m, 16);
    }
    if (valid && j < 4) {
        float s = (j == 0) ? s0 : (j == 1) ? s1 : (j == 2) ? s2 : s3;
        s += sp1b[j] + xv[10] * sp1W[j * 19 + 16] + xv[11] * sp1W[j * 19 + 17]
           + xv[12] * sp1W[j * 19 + 18];
        float hv = (s > 0.f) ? s : expm1f(s);
        float* nb = nrec1 + (size_t)n * 16;
        float sv, cv; sincosf(0.5f * PI_F * tanhf(hv), &sv, &cv);
        nb[2 * j]     = cv;
        nb[2 * j + 1] = sv;
        nb[12 + j]    = hv;
        float ds = hv * a1W[j];
        float dd = hv * a1W[4 + j];
        ds += __shfl_xor(ds, 1); ds += __shfl_xor(ds, 2);
        dd += __shfl_xor(dd, 1); dd += __shfl_xor(dd, 2);
        if (j == 0) { nb[8] = ds; hdd1[n] = dd; }
    }
}

// ---------------- offsets (deg+1 incl. self-loop) ----------------
__global__ __launch_bounds__(1024) void k_scan(
    const int* __restrict__ deg, int* __restrict__ off,
    int* __restrict__ cur, int N)
{
    __shared__ int part[1024];
    const int t = threadIdx.x;
    const int chunk = (N + 1023) / 1024;
    const int lo = t * chunk;
    const int hi = min(lo + chunk, N);
    int s = 0;
    for (int i = lo; i < hi; ++i) s += deg[i] + 1;
    part[t] = s;
    __syncthreads();
    for (int d = 1; d < 1024; d <<= 1) {
        int y = (t >= d) ? part[t - d] : 0;
        __syncthreads();
        part[t] += y;
        __syncthreads();
    }
    int run = part[t] - s;
    for (int i = lo; i < hi; ++i) { off[i] = run; cur[i] = run; run += deg[i] + 1; }
}

// ---------------- CSR fill: {src|dst<<16, |ea|, cos, sin} (incl. self-loops) ----------------
__global__ __launch_bounds__(256) void k_fill(
    const int* __restrict__ ei, const float* __restrict__ ea,
    int* __restrict__ cur, float4* __restrict__ rec, int E, int N)
{
    int idx = blockIdx.x * 256 + threadIdx.x;
    if (idx >= E + N) return;
    int src, d; float ev;
    if (idx < E) { src = ei[idx]; d = ei[E + idx]; ev = ea[idx]; }
    else         { src = idx - E; d = src;         ev = 1.0f;    }
    int slot = atomicAdd(&cur[d], 1);
    float scv, ccv; sincosf(0.5f * PI_F * tanhf(ev), &scv, &ccv);
    float4 r;
    r.x = __int_as_float(src | (d << 16));   // N < 65536
    r.y = fabsf(ev);
    r.z = ccv; r.w = scv;
    rec[slot] = r;
}

// ---------------- quantum gate helpers (used by k_gmat only) ----------------
template <int STR>
__device__ __forceinline__ void ry_g(float (&sr)[16], float (&si)[16], float c, float s) {
#pragma unroll
    for (int i0 = 0; i0 < 16; ++i0) {
        if (i0 & STR) continue;
        int i1 = i0 | STR;
        float a0r = sr[i0], a0i = si[i0], a1r = sr[i1], a1i = si[i1];
        sr[i0] = c * a0r - s * a1r; si[i0] = c * a0i - s * a1i;
        sr[i1] = s * a0r + c * a1r; si[i1] = s * a0i + c * a1i;
    }
}
template <int STR>
__device__ __forceinline__ void rz_g(float (&sr)[16], float (&si)[16], float c, float s) {
#pragma unroll
    for (int i = 0; i < 16; ++i) {
        float r = sr[i], im = si[i];
        if (i & STR) { sr[i] = r * c - im * s; si[i] = im * c + r * s; }
        else         { sr[i] = r * c + im * s; si[i] = im * c - r * s; }
    }
}
template <int SC, int ST>
__device__ __forceinline__ void cnot_g(float (&sr)[16], float (&si)[16]) {
#pragma unroll
    for (int i = 0; i < 16; ++i) {
        if ((i & SC) && !(i & ST)) {
            int j = i | ST;
            float tr = sr[i], ti = si[i];
            sr[i] = sr[j]; si[i] = si[j]; sr[j] = tr; si[j] = ti;
        }
    }
}

// ---------------- build weight-block matrices G[layer][rep] (16x16 complex) ----------------
// Column col of G_r = weight block applied to basis vector e_col (final RZ of
// rep2/d1 dropped — dies in |.|^2 past the CNOT permutation; validated R7).
__global__ __launch_bounds__(128) void k_gmat(
    const float* __restrict__ q1w, const float* __restrict__ q2w,
    float* __restrict__ Gtab)
{
    int t = threadIdx.x;
    if (t >= 96) return;
    int layer = t / 48, rem = t % 48, rep = rem / 16, col = rem % 16;
    const float* qw = layer ? q2w : q1w;
    float sr[16], si[16];
#pragma unroll
    for (int i = 0; i < 16; ++i) { sr[i] = 0.f; si[i] = 0.f; }
    sr[col] = 1.f;
#pragma unroll
    for (int d = 0; d < 2; ++d) {
        float cy, sy, cz, sz;
        sincosf(0.5f * qw[(rep * 2 + d) * 2 + 0], &sy, &cy);
        sincosf(0.5f * qw[(rep * 2 + d) * 2 + 1], &sz, &cz);
        bool lastd = (rep == 2) && (d == 1);
        ry_g<8>(sr, si, cy, sy); if (!lastd) rz_g<8>(sr, si, cz, sz);
        ry_g<4>(sr, si, cy, sy); if (!lastd) rz_g<4>(sr, si, cz, sz);
        ry_g<2>(sr, si, cy, sy); if (!lastd) rz_g<2>(sr, si, cz, sz);
        ry_g<1>(sr, si, cy, sy); if (!lastd) rz_g<1>(sr, si, cz, sz);
        if (d == 0) { cnot_g<8, 4>(sr, si); cnot_g<2, 1>(sr, si); }
        else        { cnot_g<4, 2>(sr, si); }
    }
    float* g = Gtab + layer * 1536 + rep * 512;
#pragma unroll
    for (int i = 0; i < 16; ++i) {
        g[(i * 16 + col) * 2 + 0] = sr[i];
        g[(i * 16 + col) * 2 + 1] = si[i];
    }
}

// ---------------- per-node M^w precompute: 16 lanes/node ----------------
// Element index = lane (wire0=bit8). K v[i] = bit8 ? v[i^8] : -v[i^8].
// Butterfly across lanes for R123; G matvec via shfl broadcast + LDS G (stride 17).
__global__ __launch_bounds__(256) void k_prep(
    const float* __restrict__ nrec, const float* __restrict__ Gl,
    float* __restrict__ T, int N)
{
    __shared__ float gr[3][16 * 17], gi[3][16 * 17];
    for (int idx = threadIdx.x; idx < 3 * 256; idx += 256) {
        int rep = idx >> 8, rc = idx & 255, i = rc >> 4, jj = rc & 15;
        gr[rep][i * 17 + jj] = Gl[rep * 512 + rc * 2 + 0];
        gi[rep][i * 17 + jj] = Gl[rep * 512 + rc * 2 + 1];
    }
    __syncthreads();

    const int lane = threadIdx.x & 15;
    const int n = blockIdx.x * 16 + (threadIdx.x >> 4);
    if (n >= N) return;
    const float* nb = nrec + (size_t)n * 16;
    const float c1 = nb[2], s1 = nb[3], c2 = nb[4], s2 = nb[5], c3 = nb[6], s3 = nb[7];

    // stage 0: sA = R123 e0 (real, wire0=|0>), sB = K sA
    float pa = (lane & 8) ? 0.f
             : ((lane & 4) ? s1 : c1) * ((lane & 2) ? s2 : c2) * ((lane & 1) ? s3 : c3);
    float pb;
    { float t = __shfl_xor(pa, 8, 16); pb = (lane & 8) ? t : -t; }

    // G0 on two real vectors -> complex a, b
    float ar = 0.f, ai = 0.f, br = 0.f, bi = 0.f;
#pragma unroll
    for (int jj = 0; jj < 16; ++jj) {
        float Gr = gr[0][lane * 17 + jj], Gi = gi[0][lane * 17 + jj];
        float xa = __shfl(pa, jj, 16), xb = __shfl(pb, jj, 16);
        ar += Gr * xa; ai += Gi * xa; br += Gr * xb; bi += Gi * xb;
    }

    // R123 butterfly macro (across lanes)
#define BFLY(vr, vi, STR, cc, ss) { \
    float tr_ = __shfl_xor(vr, STR, 16), ti_ = __shfl_xor(vi, STR, 16); \
    float sg_ = (lane & STR) ? (ss) : -(ss); \
    vr = (cc) * vr + sg_ * tr_; vi = (cc) * vi + sg_ * ti_; }
#define R123(vr, vi) { BFLY(vr, vi, 4, c1, s1) BFLY(vr, vi, 2, c2, s2) BFLY(vr, vi, 1, c3, s3) }
#define KAPP(orr, oii, xr, xi) { \
    float tr_ = __shfl_xor(xr, 8, 16), ti_ = __shfl_xor(xi, 8, 16); \
    orr = (lane & 8) ? tr_ : -tr_; oii = (lane & 8) ? ti_ : -ti_; }

    R123(ar, ai) R123(br, bi)

    // X2 branch: s00=a(K:0), s01=Ka(1), s10=b(1), s11=Kb(2)
    float sr4[4], si4[4];
    sr4[0] = ar; si4[0] = ai;
    KAPP(sr4[1], si4[1], ar, ai)
    sr4[2] = br; si4[2] = bi;
    KAPP(sr4[3], si4[3], br, bi)

    // G1 on 4 vectors
    float nr4[4] = {0.f, 0.f, 0.f, 0.f}, ni4[4] = {0.f, 0.f, 0.f, 0.f};
#pragma unroll
    for (int jj = 0; jj < 16; ++jj) {
        float Gr = gr[1][lane * 17 + jj], Gi = gi[1][lane * 17 + jj];
#pragma unroll
        for (int v = 0; v < 4; ++v) {
            float xr = __shfl(sr4[v], jj, 16), xi = __shfl(si4[v], jj, 16);
            nr4[v] += Gr * xr - Gi * xi;
            ni4[v] += Gr * xi + Gi * xr;
        }
    }
#pragma unroll
    for (int v = 0; v < 4; ++v) { R123(nr4[v], ni4[v]) }

    // group by K-count BEFORE G2 (G2 linear):
    // g0 = s00; g1 = (s01+s10) + K s00; g2 = s11 + K(s01+s10); g3 = K s11
    float gr4[4], gi4[4];
    float m01r = nr4[1] + nr4[2], m01i = ni4[1] + ni4[2];
    gr4[0] = nr4[0]; gi4[0] = ni4[0];
    { float kr, ki; KAPP(kr, ki, nr4[0], ni4[0]) gr4[1] = m01r + kr; gi4[1] = m01i + ki; }
    { float kr, ki; KAPP(kr, ki, m01r, m01i)     gr4[2] = nr4[3] + kr; gi4[2] = ni4[3] + ki; }
    { float kr, ki; KAPP(kr, ki, nr4[3], ni4[3]) gr4[3] = kr; gi4[3] = ki; }

    // G2 on the 4 group sums -> v0..v3
    float vr4[4] = {0.f, 0.f, 0.f, 0.f}, vi4[4] = {0.f, 0.f, 0.f, 0.f};
#pragma unroll
    for (int jj = 0; jj < 16; ++jj) {
        float Gr = gr[2][lane * 17 + jj], Gi = gi[2][lane * 17 + jj];
#pragma unroll
        for (int v = 0; v < 4; ++v) {
            float xr = __shfl(gr4[v], jj, 16), xi = __shfl(gi4[v], jj, 16);
            vr4[v] += Gr * xr - Gi * xi;
            vi4[v] += Gr * xi + Gi * xr;
        }
    }

    // pair products p_kl (k<=l), then 16-lane WHT: lane L holds
    // sum_i (-1)^{popcnt(i&L)} p_i  -> lanes 8,4,2,1 = wires 0..3 signed sums
    float p[10];
    {
        int idx = 0;
#pragma unroll
        for (int k = 0; k < 4; ++k)
#pragma unroll
            for (int l = 0; l < 4; ++l) {
                if (l < k) continue;
                p[idx++] = vr4[k] * vr4[l] + vi4[k] * vi4[l];
            }
    }
#pragma unroll
    for (int pi = 0; pi < 10; ++pi) {
        float v = p[pi];
#pragma unroll
        for (int m = 8; m >= 1; m >>= 1) {
            float t = __shfl_xor(v, m, 16);
            v = (lane & m) ? (t - v) : (v + t);
        }
        p[pi] = v;
    }

    float* Tb = T + (size_t)n * 48;
    int w = (lane == 8) ? 0 : (lane == 4) ? 1 : (lane == 2) ? 2 : (lane == 1) ? 3 : -1;
    if (w >= 0) {
#pragma unroll
        for (int pi = 0; pi < 10; ++pi) {
            float mult = (pi == 0 || pi == 4 || pi == 7 || pi == 9) ? 1.f : 2.f;
            Tb[w * 10 + pi] = mult * p[pi];
        }
    }
    if (lane == 0) { Tb[40] = nb[0]; Tb[41] = nb[1]; Tb[42] = nb[8]; Tb[43] = 0.f; }
#undef BFLY
#undef R123
#undef KAPP
}

// segmented wave reduce over equal-dst runs + atomic by segment-last lane
__device__ __forceinline__ void segreduce(
    int dst, int lane, float a0, float a1, float a2, float a3, float a4,
    float* __restrict__ S)
{
    int prevd = __shfl_up(dst, 1);
    bool head = (lane == 0) || (prevd != dst);
    unsigned long long hm = __ballot(head);
    unsigned long long below = (2ull << lane) - 1ull;
    int H = 63 - __clzll((long long)(hm & below));
    int dist = lane - H;
#pragma unroll
    for (int st = 1; st < 64; st <<= 1) {
        float t0 = __shfl_up(a0, st), t1 = __shfl_up(a1, st),
              t2 = __shfl_up(a2, st), t3 = __shfl_up(a3, st),
              t4 = __shfl_up(a4, st);
        if (dist >= st) { a0 += t0; a1 += t1; a2 += t2; a3 += t3; a4 += t4; }
    }
    int nextd = __shfl_down(dst, 1);
    bool lastl = (lane == 63) || (dst != nextd);
    if (lastl && dst >= 0) {
        float* sbase = S + (size_t)dst * 5;
        atomicAdd(sbase + 0, a0); atomicAdd(sbase + 1, a1);
        atomicAdd(sbase + 2, a2); atomicAdd(sbase + 3, a3);
        atomicAdd(sbase + 4, a4);
    }
}

// ---------------- edge kernel: quadratic form z_w = c^T M^w c ----------------
__global__ __launch_bounds__(256) void k_edge(
    const float4* __restrict__ rec, const float* __restrict__ T,
    const float* __restrict__ hdd, float* __restrict__ S, int EN)
{
    const int slot = blockIdx.x * 256 + threadIdx.x;
    const int lane = threadIdx.x & 63;
    int dst = -1;
    float acc0 = 0.f, acc1 = 0.f, acc2 = 0.f, acc3 = 0.f, acc4 = 0.f;

    if (slot < EN) {
        float4 r = rec[slot];
        int ids = __float_as_int(r.x);
        int src = ids & 0xFFFF;
        dst = ids >> 16;
        float aea = r.y, ccv = r.z, scv = r.w;

        const float* Tb = T + (size_t)src * 48;
        float t[44];
#pragma unroll
        for (int q = 0; q < 11; ++q) {
            float4 v4 = *reinterpret_cast<const float4*>(Tb + q * 4);
            t[q * 4 + 0] = v4.x; t[q * 4 + 1] = v4.y;
            t[q * 4 + 2] = v4.z; t[q * 4 + 3] = v4.w;
        }
        float hdN = hdd[dst];

        float mc = t[40] * ccv - t[41] * scv;
        float ms = t[41] * ccv + t[40] * scv;
        float m2 = mc * mc, s2 = ms * ms;
        float cf0 = mc * m2, cf1 = m2 * ms, cf2 = mc * s2, cf3 = ms * s2;
        float qq[10];
        qq[0] = cf0 * cf0; qq[1] = cf0 * cf1; qq[2] = cf0 * cf2; qq[3] = cf0 * cf3;
        qq[4] = cf1 * cf1; qq[5] = cf1 * cf2; qq[6] = cf1 * cf3;
        qq[7] = cf2 * cf2; qq[8] = cf2 * cf3; qq[9] = cf3 * cf3;

        float z0 = 0.f, z1 = 0.f, z2 = 0.f, z3 = 0.f;
#pragma unroll
        for (int pi = 0; pi < 10; ++pi) {
            z0 += t[pi] * qq[pi];
            z1 += t[10 + pi] * qq[pi];
            z2 += t[20 + pi] * qq[pi];
            z3 += t[30 + pi] * qq[pi];
        }

        float s0a = t[42] + hdN;
        s0a = (s0a > 0.f) ? s0a : 0.2f * s0a;
        float aexp = expf(s0a * aea);
        acc0 = aexp * z0; acc1 = aexp * z1; acc2 = aexp * z2; acc3 = aexp * z3;
        acc4 = aexp;
    }
    segreduce(dst, lane, acc0, acc1, acc2, acc3, acc4, S);
}

// ---------------- per-node update: norm + residual + LN (+proj2+dots | head) ----------------
template <bool FINAL>
__global__ __launch_bounds__(256) void k_node(
    const float* __restrict__ S, const float* __restrict__ nrec,
    const float* __restrict__ g4, const float* __restrict__ be4,
    const float* __restrict__ pW, const float* __restrict__ pb,
    const float* __restrict__ WaN, const float* __restrict__ rW,
    const float* __restrict__ rb, float* __restrict__ onrec,
    float* __restrict__ ohdd, float* __restrict__ out, int N)
{
    int n = blockIdx.x * 256 + threadIdx.x;
    if (n >= N) return;
    const float* sb = S + (size_t)n * 5;
    const float* nb = nrec + (size_t)n * 16;
    float dn = sb[4] + 1e-8f;
    float v0 = sb[0] / dn + nb[12];
    float v1 = sb[1] / dn + nb[13];
    float v2 = sb[2] / dn + nb[14];
    float v3 = sb[3] / dn + nb[15];
    float mu = 0.25f * (v0 + v1 + v2 + v3);
    float d0 = v0 - mu, d1 = v1 - mu, d2 = v2 - mu, d3 = v3 - mu;
    float var = 0.25f * (d0 * d0 + d1 * d1 + d2 * d2 + d3 * d3);
    float rs = 1.0f / sqrtf(var + 1e-5f);
    float y0 = d0 * rs * g4[0] + be4[0];
    float y1 = d1 * rs * g4[1] + be4[1];
    float y2 = d2 * rs * g4[2] + be4[2];
    float y3 = d3 * rs * g4[3] + be4[3];

    if (FINAL) {
        out[n] = rb[0] + y0 * rW[0] + y1 * rW[1] + y2 * rW[2] + y3 * rW[3];
    } else {
        y0 = fmaxf(y0, 0.f); y1 = fmaxf(y1, 0.f);
        y2 = fmaxf(y2, 0.f); y3 = fmaxf(y3, 0.f);
        float hv[4];
#pragma unroll
        for (int w = 0; w < 4; ++w) {
            float s = pb[w] + y0 * pW[w * 4 + 0] + y1 * pW[w * 4 + 1]
                    + y2 * pW[w * 4 + 2] + y3 * pW[w * 4 + 3];
            hv[w] = (s > 0.f) ? s : expm1f(s);
        }
        float* ob = onrec + (size_t)n * 16;
        float ds = 0.f, dd = 0.f;
#pragma unroll
        for (int w = 0; w < 4; ++w) {
            float sv, cv; sincosf(0.5f * PI_F * tanhf(hv[w]), &sv, &cv);
            ob[2 * w]     = cv;
            ob[2 * w + 1] = sv;
            ob[12 + w]    = hv[w];
            ds += hv[w] * WaN[w];
            dd += hv[w] * WaN[4 + w];
        }
        ob[8] = ds;
        ohdd[n] = dd;
    }
}

extern "C" void kernel_launch(void* const* d_in, const int* in_sizes, int n_in,
                              void* d_out, int out_size, void* d_ws, size_t ws_size,
                              hipStream_t stream)
{
    const float* x    = (const float*)d_in[0];
    const int*   ei   = (const int*)d_in[1];
    const float* ea   = (const float*)d_in[2];
    const float* W_ih = (const float*)d_in[3];
    const float* W_hh = (const float*)d_in[4];
    const float* b_ih = (const float*)d_in[5];
    const float* b_hh = (const float*)d_in[6];
    const float* p1W  = (const float*)d_in[7];
    const float* p1b  = (const float*)d_in[8];
    const float* a1W  = (const float*)d_in[9];
    const float* q1w  = (const float*)d_in[10];
    const float* g1   = (const float*)d_in[11];
    const float* be1  = (const float*)d_in[12];
    const float* p2W  = (const float*)d_in[13];
    const float* p2b  = (const float*)d_in[14];
    const float* a2W  = (const float*)d_in[15];
    const float* q2w  = (const float*)d_in[16];
    const float* g2   = (const float*)d_in[17];
    const float* be2  = (const float*)d_in[18];
    const float* rW   = (const float*)d_in[19];
    const float* rb   = (const float*)d_in[20];
    float* out = (float*)d_out;

    int N  = in_sizes[0] / 13;
    int E  = in_sizes[1] / 2;
    int EN = E + N;

    // workspace layout
    float* ws    = (float*)d_ws;
    float* nrec1 = ws;                           // N*16
    float* nrec2 = nrec1 + (size_t)N * 16;       // N*16
    float* hdd1  = nrec2 + (size_t)N * 16;       // N
    float* hdd2  = hdd1 + N;                     // N
    float* S1    = hdd2 + N;                     // N*5 (zeroed in k_gru)
    float* S2    = S1 + (size_t)N * 5;           // N*5 (zeroed in k_gru)
    float* Gtab  = S2 + (size_t)N * 5;           // 3072 (2 layers x 3 reps x 512)
    float* T     = Gtab + 3072;                  // N*48 (shared between layers)
    int* deg  = (int*)(T + (size_t)N * 48);      // N (memset)
    int* off  = deg + N;                         // N
    int* cur  = off + N;                         // N
    uintptr_t rp = (uintptr_t)(cur + N);
    rp = (rp + 15u) & ~(uintptr_t)15u;           // 16B align
    float4* rec = (float4*)rp;                   // EN float4

    hipMemsetAsync(deg, 0, (size_t)N * sizeof(int), stream);

    const int B = 256;
    k_gru<<<(N + 15) / 16, B, 0, stream>>>(x, W_ih, W_hh, b_ih, b_hh, p1W, p1b,
                                           a1W, ei, deg, nrec1, hdd1, S1, N, E);
    k_scan<<<1, 1024, 0, stream>>>(deg, off, cur, N);
    k_fill<<<(EN + B - 1) / B, B, 0, stream>>>(ei, ea, cur, rec, E, N);
    k_gmat<<<1, 128, 0, stream>>>(q1w, q2w, Gtab);

    // layer 1
    k_prep<<<(N + 15) / 16, B, 0, stream>>>(nrec1, Gtab, T, N);
    k_edge<<<(EN + B - 1) / B, B, 0, stream>>>(rec, T, hdd1, S1, EN);
    k_node<false><<<(N + B - 1) / B, B, 0, stream>>>(
        S1, nrec1, g1, be1, p2W, p2b, a2W, rW, rb, nrec2, hdd2, out, N);

    // layer 2
    k_prep<<<(N + 15) / 16, B, 0, stream>>>(nrec2, Gtab + 1536, T, N);
    k_edge<<<(EN + B - 1) / B, B, 0, stream>>>(rec, T, hdd2, S2, EN);
    k_node<true><<<(N + B - 1) / B, B, 0, stream>>>(
        S2, nrec2, g2, be2, p2W, p2b, a2W, rW, rb, nrec2, hdd2, out, N);
}

// Round 10
// 232.765 us; speedup vs baseline: 1.4796x; 1.0239x over previous
//
#include <hip/hip_runtime.h>
#include <math.h>

// QTGNN: GRU(10 steps, hidden16) -> QGAT layer1 -> QGAT layer2 -> linear head.
// N=10000 nodes, E=320000 edges (+N self loops). All fp32.
// R1: GRU 16 threads/node (shfl matvec).
// R2: fused attention, dropped softmax global-max (shift-invariant up to eps).
// R3: XCD-replica atomics refuted — device atomics RMW at coherence point.
// R4-R6: gather CSR + coalesced records + split attention dots.
// R7: 1 lane/edge + segmented shfl scan (46.6us/layer, VALU 60%).
// R8: 2-edge prefetch REGRESSED (TLP loss > ILP gain). Reverted.
// R9: circuit eliminated: psi = mc^3 v0 + mc^2 ms v1 + mc ms^2 v2 + ms^3 v3,
//     z_w = c^T M^w c, M^w per-src 4x4 (40 floats). absmax 0.0 — exact.
// R10: launch-count diet. Top-5 now = harness ws-poison fills (42us each,
//     not ours); our kernels all <42us; 11 dispatches of tail overhead.
//     Fuse prep(layer1) into k_gru epilogue (both 16 lanes/node) and
//     prep(layer2) into k_node1 (restructured to 16 lanes/node).
//     prep_node() is the UNCHANGED R9 algebra as a shared device fn.
//     nrec shrinks to 4-float residual. 11 -> 9 dispatches.

#define GH 16
#define SEQ 10
#define PI_F 3.14159265358979323846f

__device__ __forceinline__ float sigmoidf_(float x) { return 1.0f / (1.0f + expf(-x)); }

// ---------------- quantum gate helpers (used by k_gmat only) ----------------
template <int STR>
__device__ __forceinline__ void ry_g(float (&sr)[16], float (&si)[16], float c, float s) {
#pragma unroll
    for (int i0 = 0; i0 < 16; ++i0) {
        if (i0 & STR) continue;
        int i1 = i0 | STR;
        float a0r = sr[i0], a0i = si[i0], a1r = sr[i1], a1i = si[i1];
        sr[i0] = c * a0r - s * a1r; si[i0] = c * a0i - s * a1i;
        sr[i1] = s * a0r + c * a1r; si[i1] = s * a0i + c * a1i;
    }
}
template <int STR>
__device__ __forceinline__ void rz_g(float (&sr)[16], float (&si)[16], float c, float s) {
#pragma unroll
    for (int i = 0; i < 16; ++i) {
        float r = sr[i], im = si[i];
        if (i & STR) { sr[i] = r * c - im * s; si[i] = im * c + r * s; }
        else         { sr[i] = r * c + im * s; si[i] = im * c - r * s; }
    }
}
template <int SC, int ST>
__device__ __forceinline__ void cnot_g(float (&sr)[16], float (&si)[16]) {
#pragma unroll
    for (int i = 0; i < 16; ++i) {
        if ((i & SC) && !(i & ST)) {
            int j = i | ST;
            float tr = sr[i], ti = si[i];
            sr[i] = sr[j]; si[i] = si[j]; sr[j] = tr; si[j] = ti;
        }
    }
}

// ---------------- build weight-block matrices G[layer][rep] (16x16 complex) ----------------
__global__ __launch_bounds__(128) void k_gmat(
    const float* __restrict__ q1w, const float* __restrict__ q2w,
    float* __restrict__ Gtab)
{
    int t = threadIdx.x;
    if (t >= 96) return;
    int layer = t / 48, rem = t % 48, rep = rem / 16, col = rem % 16;
    const float* qw = layer ? q2w : q1w;
    float sr[16], si[16];
#pragma unroll
    for (int i = 0; i < 16; ++i) { sr[i] = 0.f; si[i] = 0.f; }
    sr[col] = 1.f;
#pragma unroll
    for (int d = 0; d < 2; ++d) {
        float cy, sy, cz, sz;
        sincosf(0.5f * qw[(rep * 2 + d) * 2 + 0], &sy, &cy);
        sincosf(0.5f * qw[(rep * 2 + d) * 2 + 1], &sz, &cz);
        bool lastd = (rep == 2) && (d == 1);
        ry_g<8>(sr, si, cy, sy); if (!lastd) rz_g<8>(sr, si, cz, sz);
        ry_g<4>(sr, si, cy, sy); if (!lastd) rz_g<4>(sr, si, cz, sz);
        ry_g<2>(sr, si, cy, sy); if (!lastd) rz_g<2>(sr, si, cz, sz);
        ry_g<1>(sr, si, cy, sy); if (!lastd) rz_g<1>(sr, si, cz, sz);
        if (d == 0) { cnot_g<8, 4>(sr, si); cnot_g<2, 1>(sr, si); }
        else        { cnot_g<4, 2>(sr, si); }
    }
    float* g = Gtab + layer * 1536 + rep * 512;
#pragma unroll
    for (int i = 0; i < 16; ++i) {
        g[(i * 16 + col) * 2 + 0] = sr[i];
        g[(i * 16 + col) * 2 + 1] = si[i];
    }
}

// ---------------- R9-validated per-node M^w precompute (device fn) ----------------
// lane in [0,16); angle pairs (c0,s0)=wire0, (c1..s3)=wires1-3; hsd = hsdot.
// gr/gi: LDS G matrices (stride 17). Writes T[n*48 .. n*48+43].
__device__ __forceinline__ void prep_node(
    int lane, int n, float c0, float s0, float c1, float s1,
    float c2, float s2, float c3, float s3, float hsd,
    const float (&gr)[3][16 * 17], const float (&gi)[3][16 * 17],
    float* __restrict__ T)
{
    float pa = (lane & 8) ? 0.f
             : ((lane & 4) ? s1 : c1) * ((lane & 2) ? s2 : c2) * ((lane & 1) ? s3 : c3);
    float pb;
    { float t = __shfl_xor(pa, 8, 16); pb = (lane & 8) ? t : -t; }

    float ar = 0.f, ai = 0.f, br = 0.f, bi = 0.f;
#pragma unroll
    for (int jj = 0; jj < 16; ++jj) {
        float Gr = gr[0][lane * 17 + jj], Gi = gi[0][lane * 17 + jj];
        float xa = __shfl(pa, jj, 16), xb = __shfl(pb, jj, 16);
        ar += Gr * xa; ai += Gi * xa; br += Gr * xb; bi += Gi * xb;
    }

#define BFLY(vr, vi, STR, cc, ss) { \
    float tr_ = __shfl_xor(vr, STR, 16), ti_ = __shfl_xor(vi, STR, 16); \
    float sg_ = (lane & STR) ? (ss) : -(ss); \
    vr = (cc) * vr + sg_ * tr_; vi = (cc) * vi + sg_ * ti_; }
#define R123(vr, vi) { BFLY(vr, vi, 4, c1, s1) BFLY(vr, vi, 2, c2, s2) BFLY(vr, vi, 1, c3, s3) }
#define KAPP(orr, oii, xr, xi) { \
    float tr_ = __shfl_xor(xr, 8, 16), ti_ = __shfl_xor(xi, 8, 16); \
    orr = (lane & 8) ? tr_ : -tr_; oii = (lane & 8) ? ti_ : -ti_; }

    R123(ar, ai) R123(br, bi)

    float sr4[4], si4[4];
    sr4[0] = ar; si4[0] = ai;
    KAPP(sr4[1], si4[1], ar, ai)
    sr4[2] = br; si4[2] = bi;
    KAPP(sr4[3], si4[3], br, bi)

    float nr4[4] = {0.f, 0.f, 0.f, 0.f}, ni4[4] = {0.f, 0.f, 0.f, 0.f};
#pragma unroll
    for (int jj = 0; jj < 16; ++jj) {
        float Gr = gr[1][lane * 17 + jj], Gi = gi[1][lane * 17 + jj];
#pragma unroll
        for (int v = 0; v < 4; ++v) {
            float xr = __shfl(sr4[v], jj, 16), xi = __shfl(si4[v], jj, 16);
            nr4[v] += Gr * xr - Gi * xi;
            ni4[v] += Gr * xi + Gi * xr;
        }
    }
#pragma unroll
    for (int v = 0; v < 4; ++v) { R123(nr4[v], ni4[v]) }

    float gr4[4], gi4[4];
    float m01r = nr4[1] + nr4[2], m01i = ni4[1] + ni4[2];
    gr4[0] = nr4[0]; gi4[0] = ni4[0];
    { float kr, ki; KAPP(kr, ki, nr4[0], ni4[0]) gr4[1] = m01r + kr; gi4[1] = m01i + ki; }
    { float kr, ki; KAPP(kr, ki, m01r, m01i)     gr4[2] = nr4[3] + kr; gi4[2] = ni4[3] + ki; }
    { float kr, ki; KAPP(kr, ki, nr4[3], ni4[3]) gr4[3] = kr; gi4[3] = ki; }

    float vr4[4] = {0.f, 0.f, 0.f, 0.f}, vi4[4] = {0.f, 0.f, 0.f, 0.f};
#pragma unroll
    for (int jj = 0; jj < 16; ++jj) {
        float Gr = gr[2][lane * 17 + jj], Gi = gi[2][lane * 17 + jj];
#pragma unroll
        for (int v = 0; v < 4; ++v) {
            float xr = __shfl(gr4[v], jj, 16), xi = __shfl(gi4[v], jj, 16);
            vr4[v] += Gr * xr - Gi * xi;
            vi4[v] += Gr * xi + Gi * xr;
        }
    }

    float p[10];
    {
        int idx = 0;
#pragma unroll
        for (int k = 0; k < 4; ++k)
#pragma unroll
            for (int l = 0; l < 4; ++l) {
                if (l < k) continue;
                p[idx++] = vr4[k] * vr4[l] + vi4[k] * vi4[l];
            }
    }
#pragma unroll
    for (int pi = 0; pi < 10; ++pi) {
        float v = p[pi];
#pragma unroll
        for (int m = 8; m >= 1; m >>= 1) {
            float t = __shfl_xor(v, m, 16);
            v = (lane & m) ? (t - v) : (v + t);
        }
        p[pi] = v;
    }

    float* Tb = T + (size_t)n * 48;
    int w = (lane == 8) ? 0 : (lane == 4) ? 1 : (lane == 2) ? 2 : (lane == 1) ? 3 : -1;
    if (w >= 0) {
#pragma unroll
        for (int pi = 0; pi < 10; ++pi) {
            float mult = (pi == 0 || pi == 4 || pi == 7 || pi == 9) ? 1.f : 2.f;
            Tb[w * 10 + pi] = mult * p[pi];
        }
    }
    if (lane == 0) { Tb[40] = c0; Tb[41] = s0; Tb[42] = hsd; Tb[43] = 0.f; }
#undef BFLY
#undef R123
#undef KAPP
}

// ---------------- GRU (16 threads/node) + proj1 + FUSED layer-1 prep
//                  + dst-degree histogram + S zeroing ----------------
__global__ __launch_bounds__(256) void k_gru(
    const float* __restrict__ x, const float* __restrict__ W_ih,
    const float* __restrict__ W_hh, const float* __restrict__ b_ih,
    const float* __restrict__ b_hh, const float* __restrict__ p1W,
    const float* __restrict__ p1b, const float* __restrict__ a1W,
    const float* __restrict__ Gl, const int* __restrict__ ei,
    int* __restrict__ deg, float* __restrict__ nres1,
    float* __restrict__ hdd1, float* __restrict__ T,
    float* __restrict__ Sz, int N, int E)
{
    for (int i = blockIdx.x * 256 + threadIdx.x; i < N * 10; i += gridDim.x * 256)
        Sz[i] = 0.f;
    for (int e = blockIdx.x * 256 + threadIdx.x; e < E; e += gridDim.x * 256)
        atomicAdd(&deg[ei[E + e]], 1);

    __shared__ float sW[48 * 16];
    __shared__ float sp1W[4 * 19], sp1b[4];
    __shared__ float gr[3][16 * 17], gi[3][16 * 17];
    for (int i = threadIdx.x; i < 48 * 16; i += 256) sW[i] = W_hh[i];
    if (threadIdx.x < 76) sp1W[threadIdx.x] = p1W[threadIdx.x];
    if (threadIdx.x < 4) sp1b[threadIdx.x] = p1b[threadIdx.x];
    for (int idx = threadIdx.x; idx < 3 * 256; idx += 256) {
        int rep = idx >> 8, rc = idx & 255, i = rc >> 4, jj = rc & 15;
        gr[rep][i * 17 + jj] = Gl[rep * 512 + rc * 2 + 0];
        gi[rep][i * 17 + jj] = Gl[rep * 512 + rc * 2 + 1];
    }
    __syncthreads();

    const int j = threadIdx.x & 15;
    const int n = blockIdx.x * 16 + (threadIdx.x >> 4);
    const bool valid = (n < N);

    float wr[GH], wz[GH], wn[GH];
#pragma unroll
    for (int k = 0; k < GH; ++k) {
        wr[k] = sW[j * 16 + k];
        wz[k] = sW[(16 + j) * 16 + k];
        wn[k] = sW[(32 + j) * 16 + k];
    }
    float wir = W_ih[j], wiz = W_ih[16 + j], win_ = W_ih[32 + j];
    float bir = b_ih[j], biz = b_ih[16 + j], bin_ = b_ih[32 + j];
    float brr = b_hh[j], brz = b_hh[16 + j], brn = b_hh[32 + j];

    float xv[13];
#pragma unroll
    for (int t = 0; t < 13; ++t) xv[t] = valid ? x[n * 13 + t] : 0.f;

    float h = 0.f;
#pragma unroll
    for (int t = 0; t < SEQ; ++t) {
        float xt = xv[t];
        float ghr = brr, ghz = brz, ghn = brn;
#pragma unroll
        for (int k = 0; k < GH; ++k) {
            float hk = __shfl(h, k, 16);
            ghr += wr[k] * hk; ghz += wz[k] * hk; ghn += wn[k] * hk;
        }
        float r  = sigmoidf_(xt * wir + bir + ghr);
        float z  = sigmoidf_(xt * wiz + biz + ghz);
        float nv = tanhf(xt * win_ + bin_ + r * ghn);
        h = (1.f - z) * nv + z * h;
    }

    // proj1 via 16-lane butterfly
    float b0 = h * sp1W[0 * 19 + j];
    float b1 = h * sp1W[1 * 19 + j];
    float b2 = h * sp1W[2 * 19 + j];
    float b3 = h * sp1W[3 * 19 + j];
#pragma unroll
    for (int m = 1; m < 16; m <<= 1) {
        b0 += __shfl_xor(b0, m, 16);
        b1 += __shfl_xor(b1, m, 16);
        b2 += __shfl_xor(b2, m, 16);
        b3 += __shfl_xor(b3, m, 16);
    }

    float hv = 0.f, cv = 1.f, sv = 0.f, ds = 0.f, dd = 0.f;
    if (j < 4) {
        float s = (j == 0) ? b0 : (j == 1) ? b1 : (j == 2) ? b2 : b3;
        s += sp1b[j] + xv[10] * sp1W[j * 19 + 16] + xv[11] * sp1W[j * 19 + 17]
           + xv[12] * sp1W[j * 19 + 18];
        hv = (s > 0.f) ? s : expm1f(s);
        sincosf(0.5f * PI_F * tanhf(hv), &sv, &cv);
        ds = hv * a1W[j];
        dd = hv * a1W[4 + j];
    }
    ds += __shfl_xor(ds, 1, 16); ds += __shfl_xor(ds, 2, 16);
    dd += __shfl_xor(dd, 1, 16); dd += __shfl_xor(dd, 2, 16);

    float c0 = __shfl(cv, 0, 16), s0 = __shfl(sv, 0, 16);
    float c1 = __shfl(cv, 1, 16), s1 = __shfl(sv, 1, 16);
    float c2 = __shfl(cv, 2, 16), s2 = __shfl(sv, 2, 16);
    float c3 = __shfl(cv, 3, 16), s3 = __shfl(sv, 3, 16);
    float hsd = __shfl(ds, 0, 16);

    if (valid) {
        if (j < 4) nres1[n * 4 + j] = hv;
        if (j == 0) hdd1[n] = dd;
        prep_node(j, n, c0, s0, c1, s1, c2, s2, c3, s3, hsd, gr, gi, T);
    }
}

// ---------------- offsets (deg+1 incl. self-loop) ----------------
__global__ __launch_bounds__(1024) void k_scan(
    const int* __restrict__ deg, int* __restrict__ off,
    int* __restrict__ cur, int N)
{
    __shared__ int part[1024];
    const int t = threadIdx.x;
    const int chunk = (N + 1023) / 1024;
    const int lo = t * chunk;
    const int hi = min(lo + chunk, N);
    int s = 0;
    for (int i = lo; i < hi; ++i) s += deg[i] + 1;
    part[t] = s;
    __syncthreads();
    for (int d = 1; d < 1024; d <<= 1) {
        int y = (t >= d) ? part[t - d] : 0;
        __syncthreads();
        part[t] += y;
        __syncthreads();
    }
    int run = part[t] - s;
    for (int i = lo; i < hi; ++i) { off[i] = run; cur[i] = run; run += deg[i] + 1; }
}

// ---------------- CSR fill: {src|dst<<16, |ea|, cos, sin} (incl. self-loops) ----------------
__global__ __launch_bounds__(256) void k_fill(
    const int* __restrict__ ei, const float* __restrict__ ea,
    int* __restrict__ cur, float4* __restrict__ rec, int E, int N)
{
    int idx = blockIdx.x * 256 + threadIdx.x;
    if (idx >= E + N) return;
    int src, d; float ev;
    if (idx < E) { src = ei[idx]; d = ei[E + idx]; ev = ea[idx]; }
    else         { src = idx - E; d = src;         ev = 1.0f;    }
    int slot = atomicAdd(&cur[d], 1);
    float scv, ccv; sincosf(0.5f * PI_F * tanhf(ev), &scv, &ccv);
    float4 r;
    r.x = __int_as_float(src | (d << 16));   // N < 65536
    r.y = fabsf(ev);
    r.z = ccv; r.w = scv;
    rec[slot] = r;
}

// segmented wave reduce over equal-dst runs + atomic by segment-last lane
__device__ __forceinline__ void segreduce(
    int dst, int lane, float a0, float a1, float a2, float a3, float a4,
    float* __restrict__ S)
{
    int prevd = __shfl_up(dst, 1);
    bool head = (lane == 0) || (prevd != dst);
    unsigned long long hm = __ballot(head);
    unsigned long long below = (2ull << lane) - 1ull;
    int H = 63 - __clzll((long long)(hm & below));
    int dist = lane - H;
#pragma unroll
    for (int st = 1; st < 64; st <<= 1) {
        float t0 = __shfl_up(a0, st), t1 = __shfl_up(a1, st),
              t2 = __shfl_up(a2, st), t3 = __shfl_up(a3, st),
              t4 = __shfl_up(a4, st);
        if (dist >= st) { a0 += t0; a1 += t1; a2 += t2; a3 += t3; a4 += t4; }
    }
    int nextd = __shfl_down(dst, 1);
    bool lastl = (lane == 63) || (dst != nextd);
    if (lastl && dst >= 0) {
        float* sbase = S + (size_t)dst * 5;
        atomicAdd(sbase + 0, a0); atomicAdd(sbase + 1, a1);
        atomicAdd(sbase + 2, a2); atomicAdd(sbase + 3, a3);
        atomicAdd(sbase + 4, a4);
    }
}

// ---------------- edge kernel: quadratic form z_w = c^T M^w c ----------------
__global__ __launch_bounds__(256) void k_edge(
    const float4* __restrict__ rec, const float* __restrict__ T,
    const float* __restrict__ hdd, float* __restrict__ S, int EN)
{
    const int slot = blockIdx.x * 256 + threadIdx.x;
    const int lane = threadIdx.x & 63;
    int dst = -1;
    float acc0 = 0.f, acc1 = 0.f, acc2 = 0.f, acc3 = 0.f, acc4 = 0.f;

    if (slot < EN) {
        float4 r = rec[slot];
        int ids = __float_as_int(r.x);
        int src = ids & 0xFFFF;
        dst = ids >> 16;
        float aea = r.y, ccv = r.z, scv = r.w;

        const float* Tb = T + (size_t)src * 48;
        float t[44];
#pragma unroll
        for (int q = 0; q < 11; ++q) {
            float4 v4 = *reinterpret_cast<const float4*>(Tb + q * 4);
            t[q * 4 + 0] = v4.x; t[q * 4 + 1] = v4.y;
            t[q * 4 + 2] = v4.z; t[q * 4 + 3] = v4.w;
        }
        float hdN = hdd[dst];

        float mc = t[40] * ccv - t[41] * scv;
        float ms = t[41] * ccv + t[40] * scv;
        float m2 = mc * mc, s2 = ms * ms;
        float cf0 = mc * m2, cf1 = m2 * ms, cf2 = mc * s2, cf3 = ms * s2;
        float qq[10];
        qq[0] = cf0 * cf0; qq[1] = cf0 * cf1; qq[2] = cf0 * cf2; qq[3] = cf0 * cf3;
        qq[4] = cf1 * cf1; qq[5] = cf1 * cf2; qq[6] = cf1 * cf3;
        qq[7] = cf2 * cf2; qq[8] = cf2 * cf3; qq[9] = cf3 * cf3;

        float z0 = 0.f, z1 = 0.f, z2 = 0.f, z3 = 0.f;
#pragma unroll
        for (int pi = 0; pi < 10; ++pi) {
            z0 += t[pi] * qq[pi];
            z1 += t[10 + pi] * qq[pi];
            z2 += t[20 + pi] * qq[pi];
            z3 += t[30 + pi] * qq[pi];
        }

        float s0a = t[42] + hdN;
        s0a = (s0a > 0.f) ? s0a : 0.2f * s0a;
        float aexp = expf(s0a * aea);
        acc0 = aexp * z0; acc1 = aexp * z1; acc2 = aexp * z2; acc3 = aexp * z3;
        acc4 = aexp;
    }
    segreduce(dst, lane, acc0, acc1, acc2, acc3, acc4, S);
}

// ---------------- layer-1 node update (16 lanes/node) + FUSED layer-2 prep ----------------
__global__ __launch_bounds__(256) void k_nodeprep(
    const float* __restrict__ S, const float* __restrict__ nres,
    const float* __restrict__ g4, const float* __restrict__ be4,
    const float* __restrict__ pW, const float* __restrict__ pb,
    const float* __restrict__ WaN, const float* __restrict__ Gl,
    float* __restrict__ onres, float* __restrict__ ohdd,
    float* __restrict__ T, int N)
{
    __shared__ float gr[3][16 * 17], gi[3][16 * 17];
    for (int idx = threadIdx.x; idx < 3 * 256; idx += 256) {
        int rep = idx >> 8, rc = idx & 255, i = rc >> 4, jj = rc & 15;
        gr[rep][i * 17 + jj] = Gl[rep * 512 + rc * 2 + 0];
        gi[rep][i * 17 + jj] = Gl[rep * 512 + rc * 2 + 1];
    }
    __syncthreads();

    const int lane = threadIdx.x & 15;
    const int n = blockIdx.x * 16 + (threadIdx.x >> 4);
    if (n >= N) return;

    const float* sb = S + (size_t)n * 5;
    float dn = sb[4] + 1e-8f;
    float v0 = sb[0] / dn + nres[n * 4 + 0];
    float v1 = sb[1] / dn + nres[n * 4 + 1];
    float v2 = sb[2] / dn + nres[n * 4 + 2];
    float v3 = sb[3] / dn + nres[n * 4 + 3];
    float mu = 0.25f * (v0 + v1 + v2 + v3);
    float d0 = v0 - mu, d1 = v1 - mu, d2 = v2 - mu, d3 = v3 - mu;
    float var = 0.25f * (d0 * d0 + d1 * d1 + d2 * d2 + d3 * d3);
    float rs = 1.0f / sqrtf(var + 1e-5f);
    float y0 = fmaxf(d0 * rs * g4[0] + be4[0], 0.f);
    float y1 = fmaxf(d1 * rs * g4[1] + be4[1], 0.f);
    float y2 = fmaxf(d2 * rs * g4[2] + be4[2], 0.f);
    float y3 = fmaxf(d3 * rs * g4[3] + be4[3], 0.f);

    float hv[4];
#pragma unroll
    for (int w = 0; w < 4; ++w) {
        float s = pb[w] + y0 * pW[w * 4 + 0] + y1 * pW[w * 4 + 1]
                + y2 * pW[w * 4 + 2] + y3 * pW[w * 4 + 3];
        hv[w] = (s > 0.f) ? s : expm1f(s);
    }

    float cv = 1.f, sv = 0.f;
    if (lane < 4) sincosf(0.5f * PI_F * tanhf(hv[lane]), &sv, &cv);
    float c0 = __shfl(cv, 0, 16), s0 = __shfl(sv, 0, 16);
    float c1 = __shfl(cv, 1, 16), s1 = __shfl(sv, 1, 16);
    float c2 = __shfl(cv, 2, 16), s2 = __shfl(sv, 2, 16);
    float c3 = __shfl(cv, 3, 16), s3 = __shfl(sv, 3, 16);

    float hsd = hv[0] * WaN[0] + hv[1] * WaN[1] + hv[2] * WaN[2] + hv[3] * WaN[3];
    if (lane < 4) onres[n * 4 + lane] = hv[lane];
    if (lane == 0)
        ohdd[n] = hv[0] * WaN[4] + hv[1] * WaN[5] + hv[2] * WaN[6] + hv[3] * WaN[7];

    prep_node(lane, n, c0, s0, c1, s1, c2, s2, c3, s3, hsd, gr, gi, T);
}

// ---------------- final node update: norm + residual + LN + head ----------------
__global__ __launch_bounds__(256) void k_node2(
    const float* __restrict__ S, const float* __restrict__ nres,
    const float* __restrict__ g4, const float* __restrict__ be4,
    const float* __restrict__ rW, const float* __restrict__ rb,
    float* __restrict__ out, int N)
{
    int n = blockIdx.x * 256 + threadIdx.x;
    if (n >= N) return;
    const float* sb = S + (size_t)n * 5;
    float dn = sb[4] + 1e-8f;
    float v0 = sb[0] / dn + nres[n * 4 + 0];
    float v1 = sb[1] / dn + nres[n * 4 + 1];
    float v2 = sb[2] / dn + nres[n * 4 + 2];
    float v3 = sb[3] / dn + nres[n * 4 + 3];
    float mu = 0.25f * (v0 + v1 + v2 + v3);
    float d0 = v0 - mu, d1 = v1 - mu, d2 = v2 - mu, d3 = v3 - mu;
    float var = 0.25f * (d0 * d0 + d1 * d1 + d2 * d2 + d3 * d3);
    float rs = 1.0f / sqrtf(var + 1e-5f);
    out[n] = rb[0]
           + (d0 * rs * g4[0] + be4[0]) * rW[0]
           + (d1 * rs * g4[1] + be4[1]) * rW[1]
           + (d2 * rs * g4[2] + be4[2]) * rW[2]
           + (d3 * rs * g4[3] + be4[3]) * rW[3];
}

extern "C" void kernel_launch(void* const* d_in, const int* in_sizes, int n_in,
                              void* d_out, int out_size, void* d_ws, size_t ws_size,
                              hipStream_t stream)
{
    const float* x    = (const float*)d_in[0];
    const int*   ei   = (const int*)d_in[1];
    const float* ea   = (const float*)d_in[2];
    const float* W_ih = (const float*)d_in[3];
    const float* W_hh = (const float*)d_in[4];
    const float* b_ih = (const float*)d_in[5];
    const float* b_hh = (const float*)d_in[6];
    const float* p1W  = (const float*)d_in[7];
    const float* p1b  = (const float*)d_in[8];
    const float* a1W  = (const float*)d_in[9];
    const float* q1w  = (const float*)d_in[10];
    const float* g1   = (const float*)d_in[11];
    const float* be1  = (const float*)d_in[12];
    const float* p2W  = (const float*)d_in[13];
    const float* p2b  = (const float*)d_in[14];
    const float* a2W  = (const float*)d_in[15];
    const float* q2w  = (const float*)d_in[16];
    const float* g2   = (const float*)d_in[17];
    const float* be2  = (const float*)d_in[18];
    const float* rW   = (const float*)d_in[19];
    const float* rb   = (const float*)d_in[20];
    float* out = (float*)d_out;

    int N  = in_sizes[0] / 13;
    int E  = in_sizes[1] / 2;
    int EN = E + N;

    // workspace layout
    float* ws    = (float*)d_ws;
    float* nres1 = ws;                           // N*4
    float* nres2 = nres1 + (size_t)N * 4;        // N*4
    float* hdd1  = nres2 + (size_t)N * 4;        // N
    float* hdd2  = hdd1 + N;                     // N
    float* S1    = hdd2 + N;                     // N*5 (zeroed in k_gru)
    float* S2    = S1 + (size_t)N * 5;           // N*5 (zeroed in k_gru)
    float* Gtab  = S2 + (size_t)N * 5;           // 3072
    float* T     = Gtab + 3072;                  // N*48 (reused across layers)
    int* deg  = (int*)(T + (size_t)N * 48);      // N (memset)
    int* off  = deg + N;                         // N
    int* cur  = off + N;                         // N
    uintptr_t rp = (uintptr_t)(cur + N);
    rp = (rp + 15u) & ~(uintptr_t)15u;           // 16B align
    float4* rec = (float4*)rp;                   // EN float4

    hipMemsetAsync(deg, 0, (size_t)N * sizeof(int), stream);

    const int B = 256;
    k_gmat<<<1, 128, 0, stream>>>(q1w, q2w, Gtab);
    k_gru<<<(N + 15) / 16, B, 0, stream>>>(x, W_ih, W_hh, b_ih, b_hh, p1W, p1b,
                                           a1W, Gtab, ei, deg, nres1, hdd1, T,
                                           S1, N, E);
    k_scan<<<1, 1024, 0, stream>>>(deg, off, cur, N);
    k_fill<<<(EN + B - 1) / B, B, 0, stream>>>(ei, ea, cur, rec, E, N);

    // layer 1
    k_edge<<<(EN + B - 1) / B, B, 0, stream>>>(rec, T, hdd1, S1, EN);
    k_nodeprep<<<(N + 15) / 16, B, 0, stream>>>(
        S1, nres1, g1, be1, p2W, p2b, a2W, Gtab + 1536, nres2, hdd2, T, N);

    // layer 2
    k_edge<<<(EN + B - 1) / B, B, 0, stream>>>(rec, T, hdd2, S2, EN);
    k_node2<<<(N + B - 1) / B, B, 0, stream>>>(S2, nres2, g2, be2, rW, rb, out, N);
}